// Round 3
// baseline (218.221 us; speedup 1.0000x reference)
//
#include <hip/hip_runtime.h>
#include <hip/hip_bf16.h>

#define Bn 2
#define Sn 4096
#define Dn 512
#define Hn 8
#define DKn 64

typedef __bf16 bf16x8 __attribute__((ext_vector_type(8)));
typedef float f32x16 __attribute__((ext_vector_type(16)));

static __device__ __forceinline__ unsigned short f2bf(float x) {
    __hip_bfloat16 h = __float2bfloat16(x);
    return *reinterpret_cast<unsigned short*>(&h);
}

static __device__ __forceinline__ uint2 pack4(float a, float b, float c, float d) {
    union { ushort4 u; uint2 v; } r;
    r.u.x = f2bf(a); r.u.y = f2bf(b); r.u.z = f2bf(c); r.u.w = f2bf(d);
    return r.v;
}

// C-layout group pair -> B/A-fragment via lane^32 exchange.
// pg0 = packed group (g=2*k2), pg1 = packed group (g=2*k2+1); hi = lane>>5.
// frag[j<4] comes from hi'=0 lane's group (2*k2+hi); frag[j>=4] from hi'=1 lane's same group.
static __device__ __forceinline__ bf16x8 xchg_frag(uint2 pg0, uint2 pg1, int hi) {
    int sx = hi ? (int)pg0.x : (int)pg1.x;
    int sy = hi ? (int)pg0.y : (int)pg1.y;
    int rx = __shfl_xor(sx, 32);
    int ry = __shfl_xor(sy, 32);
    unsigned ox = hi ? pg1.x : pg0.x;
    unsigned oy = hi ? pg1.y : pg0.y;
    union { unsigned u[4]; bf16x8 v; } f;
    f.u[0] = hi ? (unsigned)rx : ox;
    f.u[1] = hi ? (unsigned)ry : oy;
    f.u[2] = hi ? ox : (unsigned)rx;
    f.u[3] = hi ? oy : (unsigned)ry;
    return f.v;
}

// ---------- prepass: K fp32 -> Kb bf16, MFMA-A-fragment order per 64x64 tile ----------
// Kb layout: [bh][kt64][frag f=keytile*4+kstep][lane 64][j 8]
__global__ __launch_bounds__(256) void kprep_kernel(const float* __restrict__ K,
                                                    unsigned short* __restrict__ Kb) {
    const int kt = blockIdx.x, bh = blockIdx.y;
    const int b = bh >> 3, h = bh & 7;
    unsigned short* dst = Kb + ((size_t)bh * 64 + kt) * 4096;
#pragma unroll
    for (int i = 0; i < 2; ++i) {
        int c = threadIdx.x + i * 256;       // chunk 0..511
        int f = c >> 6, ln = c & 63;
        int ktile = f >> 2, ks = f & 3;
        int row = ktile * 32 + (ln & 31);
        int dk = ks * 16 + (ln >> 5) * 8;
        const float* src = K + ((size_t)(b * Sn + kt * 64 + row)) * Dn + h * 64 + dk;
        float4 a0 = *(const float4*)src;
        float4 a1 = *(const float4*)(src + 4);
        ushort4 o0; o0.x = f2bf(a0.x); o0.y = f2bf(a0.y); o0.z = f2bf(a0.z); o0.w = f2bf(a0.w);
        ushort4 o1; o1.x = f2bf(a1.x); o1.y = f2bf(a1.y); o1.z = f2bf(a1.z); o1.w = f2bf(a1.w);
        *(ushort4*)(dst + c * 8) = o0;
        *(ushort4*)(dst + c * 8 + 4) = o1;
    }
}

// ---------- prepass: V fp32 -> Vb bf16, V^T A-fragment order ----------
// Vb layout: [bh][kt64][frag f=dktile*4+kstep][lane 64][j 8]; element: row=dk, col=key
__global__ __launch_bounds__(256) void vprep_kernel(const float* __restrict__ V,
                                                    unsigned short* __restrict__ Vb) {
    const int kt = blockIdx.x, bh = blockIdx.y;
    const int b = bh >> 3, h = bh & 7;
    unsigned short* dst = Vb + ((size_t)bh * 64 + kt) * 4096;
#pragma unroll
    for (int i = 0; i < 2; ++i) {
        int c = threadIdx.x + i * 256;
        int f = c >> 6, ln = c & 63;
        int dt = f >> 2, ks = f & 3;
        int dk = dt * 32 + (ln & 31);
        int key0 = ks * 16 + (ln >> 5) * 8;
        const float* src = V + ((size_t)(b * Sn + kt * 64 + key0)) * Dn + h * 64 + dk;
        ushort4 o0, o1;
        o0.x = f2bf(src[0 * Dn]); o0.y = f2bf(src[1 * Dn]);
        o0.z = f2bf(src[2 * Dn]); o0.w = f2bf(src[3 * Dn]);
        o1.x = f2bf(src[4 * Dn]); o1.y = f2bf(src[5 * Dn]);
        o1.z = f2bf(src[6 * Dn]); o1.w = f2bf(src[7 * Dn]);
        *(ushort4*)(dst + c * 8) = o0;
        *(ushort4*)(dst + c * 8 + 4) = o1;
    }
}

// ---------- prepass: W fp32 [k][n] -> Wb bf16 B-fragment order ----------
// Wb layout: [ntile 16][kstep 32][lane 64][j 8]; element: col n, k
__global__ __launch_bounds__(256) void wprep_kernel(const float* __restrict__ W,
                                                    unsigned short* __restrict__ Wb) {
    int c = blockIdx.x * 256 + threadIdx.x;  // 0..32767
    int ln = c & 63, f = c >> 6;
    int ntile = f >> 5, ks = f & 31;
    int n = ntile * 32 + (ln & 31);
    int k0 = ks * 16 + (ln >> 5) * 8;
    ushort4 o0, o1;
    o0.x = f2bf(W[(size_t)(k0 + 0) * Dn + n]); o0.y = f2bf(W[(size_t)(k0 + 1) * Dn + n]);
    o0.z = f2bf(W[(size_t)(k0 + 2) * Dn + n]); o0.w = f2bf(W[(size_t)(k0 + 3) * Dn + n]);
    o1.x = f2bf(W[(size_t)(k0 + 4) * Dn + n]); o1.y = f2bf(W[(size_t)(k0 + 5) * Dn + n]);
    o1.z = f2bf(W[(size_t)(k0 + 6) * Dn + n]); o1.w = f2bf(W[(size_t)(k0 + 7) * Dn + n]);
    *(ushort4*)(Wb + c * 8) = o0;
    *(ushort4*)(Wb + c * 8 + 4) = o1;
}

// ---------- flash attention: 32x32x16 MFMA, 32 q/wave, in-register P transpose ----------
// grid (32 qtiles of 128, 16 bh), block 256 (4 waves).
// S^T = K.Q^T (C: row=key, col=q); p=exp2 lane-local; P^T B-frags via shfl_xor(32);
// O^T = V^T.P^T; epilogue writes proj-A-fragments to ObA.
__global__ __launch_bounds__(256) void attn_kernel(
    const float* __restrict__ Q,
    const unsigned short* __restrict__ Kb,
    const unsigned short* __restrict__ Vb,
    unsigned short* __restrict__ ObA) {   // [gmtile 256][ksg 32][lane 64][8]
    __shared__ __align__(16) unsigned short Ksh[4096];
    __shared__ __align__(16) unsigned short Vsh[4096];

    const int qt = blockIdx.x;
    const int bh = blockIdx.y;
    const int b = bh >> 3, h = bh & 7;
    const int tid = threadIdx.x;
    const int w = tid >> 6;
    const int lane = tid & 63;
    const int q = lane & 31;
    const int hi = lane >> 5;
    const int q0 = qt * 128 + w * 32;
    const float cexp = 0.18033688f;  // (1/sqrt(64)) * log2(e), folded into Q

    // Q B-frags: col=q, k(dk) = ks*16 + hi*8 + j
    bf16x8 qf[4];
    {
        const float* qp = Q + ((size_t)(b * Sn + q0 + q)) * Dn + h * 64 + hi * 8;
#pragma unroll
        for (int ks = 0; ks < 4; ++ks) {
            float4 a0 = *(const float4*)(qp + ks * 16);
            float4 a1 = *(const float4*)(qp + ks * 16 + 4);
            union { unsigned short u[8]; bf16x8 v; } f;
            f.u[0] = f2bf(a0.x * cexp); f.u[1] = f2bf(a0.y * cexp);
            f.u[2] = f2bf(a0.z * cexp); f.u[3] = f2bf(a0.w * cexp);
            f.u[4] = f2bf(a1.x * cexp); f.u[5] = f2bf(a1.y * cexp);
            f.u[6] = f2bf(a1.z * cexp); f.u[7] = f2bf(a1.w * cexp);
            qf[ks] = f.v;
        }
    }

    f32x16 oacc[2];
#pragma unroll
    for (int t = 0; t < 2; ++t)
#pragma unroll
        for (int r = 0; r < 16; ++r) oacc[t][r] = 0.f;
    float l_ = 0.f;

    const unsigned short* kg = Kb + (size_t)bh * (64 * 4096);
    const unsigned short* vg = Vb + (size_t)bh * (64 * 4096);

    for (int kt = 0; kt < 64; ++kt) {
        __syncthreads();
        {
            const unsigned short* ks_ = kg + (size_t)kt * 4096;
            const unsigned short* vs_ = vg + (size_t)kt * 4096;
            uint4 k0 = *(const uint4*)(ks_ + tid * 8);
            uint4 k1 = *(const uint4*)(ks_ + 2048 + tid * 8);
            uint4 v0 = *(const uint4*)(vs_ + tid * 8);
            uint4 v1 = *(const uint4*)(vs_ + 2048 + tid * 8);
            *(uint4*)&Ksh[tid * 8] = k0;
            *(uint4*)&Ksh[2048 + tid * 8] = k1;
            *(uint4*)&Vsh[tid * 8] = v0;
            *(uint4*)&Vsh[2048 + tid * 8] = v1;
        }
        __syncthreads();

        // S^T = K . Q^T
        f32x16 sacc[2];
#pragma unroll
        for (int t = 0; t < 2; ++t)
#pragma unroll
            for (int r = 0; r < 16; ++r) sacc[t][r] = 0.f;
#pragma unroll
        for (int ks = 0; ks < 4; ++ks) {
            bf16x8 ka0 = *(const bf16x8*)&Ksh[(0 * 4 + ks) * 512 + lane * 8];
            bf16x8 ka1 = *(const bf16x8*)&Ksh[(1 * 4 + ks) * 512 + lane * 8];
            sacc[0] = __builtin_amdgcn_mfma_f32_32x32x16_bf16(ka0, qf[ks], sacc[0], 0, 0, 0);
            sacc[1] = __builtin_amdgcn_mfma_f32_32x32x16_bf16(ka1, qf[ks], sacc[1], 0, 0, 0);
        }

        // p = exp2(s); lane-local l accumulation
        float p[2][16];
#pragma unroll
        for (int t = 0; t < 2; ++t) {
            float s0 = 0.f, s1 = 0.f;
#pragma unroll
            for (int r = 0; r < 16; r += 2) {
                float e0 = __builtin_amdgcn_exp2f(sacc[t][r]);
                float e1 = __builtin_amdgcn_exp2f(sacc[t][r + 1]);
                p[t][r] = e0; p[t][r + 1] = e1;
                s0 += e0; s1 += e1;
            }
            l_ += s0 + s1;
        }

        // O^T += V^T . P^T  (P B-frags built in-register)
#pragma unroll
        for (int kp = 0; kp < 4; ++kp) {
            const int c = kp >> 1, k2 = kp & 1;
            uint2 pg0 = pack4(p[c][8 * k2 + 0], p[c][8 * k2 + 1], p[c][8 * k2 + 2], p[c][8 * k2 + 3]);
            uint2 pg1 = pack4(p[c][8 * k2 + 4], p[c][8 * k2 + 5], p[c][8 * k2 + 6], p[c][8 * k2 + 7]);
            bf16x8 pb = xchg_frag(pg0, pg1, hi);
            bf16x8 va0 = *(const bf16x8*)&Vsh[(0 * 4 + kp) * 512 + lane * 8];
            bf16x8 va1 = *(const bf16x8*)&Vsh[(1 * 4 + kp) * 512 + lane * 8];
            oacc[0] = __builtin_amdgcn_mfma_f32_32x32x16_bf16(va0, pb, oacc[0], 0, 0, 0);
            oacc[1] = __builtin_amdgcn_mfma_f32_32x32x16_bf16(va1, pb, oacc[1], 0, 0, 0);
        }
    }

    // epilogue: l reduce (partner holds other half of keys), normalize, emit proj A-frags
    l_ += __shfl_xor(l_, 32);
    const float li = 1.f / l_;
    const int gm = b * 128 + qt * 4 + w;
#pragma unroll
    for (int ksg = 0; ksg < 4; ++ksg) {
        const int dt = ksg >> 1, k2 = ksg & 1;
        uint2 pg0 = pack4(oacc[dt][8 * k2 + 0] * li, oacc[dt][8 * k2 + 1] * li,
                          oacc[dt][8 * k2 + 2] * li, oacc[dt][8 * k2 + 3] * li);
        uint2 pg1 = pack4(oacc[dt][8 * k2 + 4] * li, oacc[dt][8 * k2 + 5] * li,
                          oacc[dt][8 * k2 + 6] * li, oacc[dt][8 * k2 + 7] * li);
        bf16x8 frag = xchg_frag(pg0, pg1, hi);
        union { bf16x8 v; uint4 u; } fu; fu.v = frag;
        *(uint4*)&ObA[((size_t)(gm * 32 + h * 4 + ksg) * 64 + lane) * 8] = fu.u;
    }
}

// ---------- projection GEMM: out = A @ W + b (A,W fragment-ordered bf16) ----------
// grid (64 mt of 128 rows, 8 nt of 64 cols), block 256 (4 waves, 32 rows each).
__global__ __launch_bounds__(256) void proj_kernel(
    const unsigned short* __restrict__ ObA,  // [256][32][64][8]
    const unsigned short* __restrict__ Wb,   // [16][32][64][8]
    const float* __restrict__ bias,
    float* __restrict__ out) {
    __shared__ __align__(16) unsigned short Ash[8192];
    __shared__ __align__(16) unsigned short Wsh[4096];

    const int mt = blockIdx.x;
    const int nt = blockIdx.y;
    const int tid = threadIdx.x;
    const int w = tid >> 6;
    const int lane = tid & 63;
    const int q = lane & 31;
    const int hi = lane >> 5;

    f32x16 acc[2];
#pragma unroll
    for (int t = 0; t < 2; ++t)
#pragma unroll
        for (int r = 0; r < 16; ++r) acc[t][r] = 0.f;

    for (int kt = 0; kt < 8; ++kt) {
        __syncthreads();
#pragma unroll
        for (int i = 0; i < 4; ++i) {
            int ci = (tid >> 6) + i * 4;     // 0..15
            int ml = ci >> 2, ksl = ci & 3;
            *(uint4*)&Ash[ci * 512 + lane * 8] =
                *(const uint4*)(ObA + (((size_t)(mt * 4 + ml) * 32 + kt * 4 + ksl) * 64 + lane) * 8);
        }
#pragma unroll
        for (int i = 0; i < 2; ++i) {
            int ci = (tid >> 6) + i * 4;     // 0..7
            int ntl = ci >> 2, ksl = ci & 3;
            *(uint4*)&Wsh[ci * 512 + lane * 8] =
                *(const uint4*)(Wb + (((size_t)(nt * 2 + ntl) * 32 + kt * 4 + ksl) * 64 + lane) * 8);
        }
        __syncthreads();

#pragma unroll
        for (int ks = 0; ks < 4; ++ks) {
            bf16x8 a  = *(const bf16x8*)&Ash[(w * 4 + ks) * 512 + lane * 8];
            bf16x8 b0 = *(const bf16x8*)&Wsh[(0 * 4 + ks) * 512 + lane * 8];
            bf16x8 b1 = *(const bf16x8*)&Wsh[(4 + ks) * 512 + lane * 8];
            acc[0] = __builtin_amdgcn_mfma_f32_32x32x16_bf16(a, b0, acc[0], 0, 0, 0);
            acc[1] = __builtin_amdgcn_mfma_f32_32x32x16_bf16(a, b1, acc[1], 0, 0, 0);
        }
    }

#pragma unroll
    for (int ntl = 0; ntl < 2; ++ntl) {
        int col = nt * 64 + ntl * 32 + q;
        float bv = bias[col];
#pragma unroll
        for (int reg = 0; reg < 16; ++reg) {
            int row = mt * 128 + w * 32 + (reg & 3) + 8 * (reg >> 2) + 4 * hi;
            out[(size_t)row * Dn + col] = acc[ntl][reg] + bv;
        }
    }
}

extern "C" void kernel_launch(void* const* d_in, const int* in_sizes, int n_in,
                              void* d_out, int out_size, void* d_ws, size_t ws_size,
                              hipStream_t stream) {
    const float* Q = (const float*)d_in[0];
    const float* K = (const float*)d_in[1];
    const float* V = (const float*)d_in[2];
    const float* W = (const float*)d_in[3];
    const float* bo = (const float*)d_in[4];
    float* out = (float*)d_out;

    char* ws = (char*)d_ws;
    unsigned short* Kb  = (unsigned short*)(ws);                 // 8 MB
    unsigned short* Vb  = (unsigned short*)(ws + 8388608);       // 8 MB
    unsigned short* Wb  = (unsigned short*)(ws + 16777216);      // 512 KB
    unsigned short* ObA = (unsigned short*)(ws + 17301504);      // 8 MB

    kprep_kernel<<<dim3(64, 16), 256, 0, stream>>>(K, Kb);
    vprep_kernel<<<dim3(64, 16), 256, 0, stream>>>(V, Vb);
    wprep_kernel<<<128, 256, 0, stream>>>(W, Wb);
    attn_kernel<<<dim3(32, 16), 256, 0, stream>>>(Q, Kb, Vb, ObA);
    proj_kernel<<<dim3(64, 8), 256, 0, stream>>>(ObA, Wb, bo, out);
}

// Round 4
// 193.466 us; speedup vs baseline: 1.1280x; 1.1280x over previous
//
#include <hip/hip_runtime.h>
#include <hip/hip_bf16.h>

#define Bn 2
#define Sn 4096
#define Dn 512
#define Hn 8

typedef __bf16 bf16x8 __attribute__((ext_vector_type(8)));
typedef float f32x16 __attribute__((ext_vector_type(16)));

// pack two f32 -> two bf16 (round-half-up): int add + v_perm_b32. 3 VALU ops.
static __device__ __forceinline__ unsigned pk2(float a, float b) {
    unsigned ua = __float_as_uint(a) + 0x8000u;
    unsigned ub = __float_as_uint(b) + 0x8000u;
    return __builtin_amdgcn_perm(ub, ua, 0x07060302u);
}

// C-layout group pair -> B/A-fragment via lane^32 exchange (groups as 2 dwords each).
static __device__ __forceinline__ bf16x8 xchg2(unsigned g0x, unsigned g0y,
                                               unsigned g1x, unsigned g1y, int hi) {
    int sx = hi ? (int)g0x : (int)g1x;
    int sy = hi ? (int)g0y : (int)g1y;
    int rx = __shfl_xor(sx, 32);
    int ry = __shfl_xor(sy, 32);
    unsigned ox = hi ? g1x : g0x;
    unsigned oy = hi ? g1y : g0y;
    union { unsigned u[4]; bf16x8 v; } f;
    f.u[0] = hi ? (unsigned)rx : ox;
    f.u[1] = hi ? (unsigned)ry : oy;
    f.u[2] = hi ? ox : (unsigned)rx;
    f.u[3] = hi ? oy : (unsigned)ry;
    return f.v;
}

// ---------- unified prepass: K,V,W fp32 -> fragment-ordered bf16 ----------
// blocks 0..1023: K -> Kb [bh][kt64][f=ktile*4+ks][lane][8]
// blocks 1024..2047: V -> Vb [bh][kt64][f=dktile*4+ks][lane][8] (V^T)
// blocks 2048..2175: W -> Wb [ntile16][kstep32][lane][8] (W^T)
__global__ __launch_bounds__(256) void prep_kernel(
    const float* __restrict__ K, const float* __restrict__ V, const float* __restrict__ W,
    unsigned short* __restrict__ Kb, unsigned short* __restrict__ Vb,
    unsigned short* __restrict__ Wb) {
    const int vb = blockIdx.x;
    const int tid = threadIdx.x;
    if (vb < 1024) {
        const int kt = vb & 63, bh = vb >> 6;
        const int b = bh >> 3, h = bh & 7;
        unsigned short* dst = Kb + ((size_t)bh * 64 + kt) * 4096;
#pragma unroll
        for (int i = 0; i < 2; ++i) {
            int c = tid + i * 256;
            int f = c >> 6, ln = c & 63;
            int ktile = f >> 2, ks = f & 3;
            int row = ktile * 32 + (ln & 31);
            int dk = ks * 16 + (ln >> 5) * 8;
            const float* src = K + ((size_t)(b * Sn + kt * 64 + row)) * Dn + h * 64 + dk;
            float4 a0 = *(const float4*)src;
            float4 a1 = *(const float4*)(src + 4);
            uint4 o;
            o.x = pk2(a0.x, a0.y); o.y = pk2(a0.z, a0.w);
            o.z = pk2(a1.x, a1.y); o.w = pk2(a1.z, a1.w);
            *(uint4*)(dst + c * 8) = o;
        }
    } else if (vb < 2048) {
        const int u = vb - 1024;
        const int kt = u & 63, bh = u >> 6;
        const int b = bh >> 3, h = bh & 7;
        unsigned short* dst = Vb + ((size_t)bh * 64 + kt) * 4096;
#pragma unroll
        for (int i = 0; i < 2; ++i) {
            int c = tid + i * 256;
            int f = c >> 6, ln = c & 63;
            int dt = f >> 2, ks = f & 3;
            int dk = dt * 32 + (ln & 31);
            int key0 = ks * 16 + (ln >> 5) * 8;
            const float* src = V + ((size_t)(b * Sn + kt * 64 + key0)) * Dn + h * 64 + dk;
            uint4 o;
            o.x = pk2(src[0 * Dn], src[1 * Dn]); o.y = pk2(src[2 * Dn], src[3 * Dn]);
            o.z = pk2(src[4 * Dn], src[5 * Dn]); o.w = pk2(src[6 * Dn], src[7 * Dn]);
            *(uint4*)(dst + c * 8) = o;
        }
    } else {
        int c = (vb - 2048) * 256 + tid;   // 0..32767
        int ln = c & 63, f = c >> 6;
        int ntile = f >> 5, ks = f & 31;
        int n = ntile * 32 + (ln & 31);
        int k0 = ks * 16 + (ln >> 5) * 8;
        uint4 o;
        o.x = pk2(W[(size_t)(k0 + 0) * Dn + n], W[(size_t)(k0 + 1) * Dn + n]);
        o.y = pk2(W[(size_t)(k0 + 2) * Dn + n], W[(size_t)(k0 + 3) * Dn + n]);
        o.z = pk2(W[(size_t)(k0 + 4) * Dn + n], W[(size_t)(k0 + 5) * Dn + n]);
        o.w = pk2(W[(size_t)(k0 + 6) * Dn + n], W[(size_t)(k0 + 7) * Dn + n]);
        *(uint4*)(Wb + c * 8) = o;
    }
}

// ---------- flash attention: 32x32x16 MFMA, intra-block key-split x2 ----------
// block 512 thr = 8 waves: waves 0-3 (half=0) keys 0..2047, waves 4-7 keys 2048..4095;
// wave pair (w4, w4+4) shares q-tile q0 = qt*128 + w4*32; pair-reduce via LDS at end.
__global__ __launch_bounds__(512, 4) void attn_kernel(
    const float* __restrict__ Q,
    const unsigned short* __restrict__ Kb,
    const unsigned short* __restrict__ Vb,
    unsigned short* __restrict__ ObA) {   // [gmtile 256][ksg 32][lane 64][8]
    __shared__ __align__(16) unsigned short KV[16384];  // 2x K(4096) + 2x V(4096)
    __shared__ float Lsh[4][64];

    const int qt = blockIdx.x;
    const int bh = blockIdx.y;
    const int b = bh >> 3, h = bh & 7;
    const int tid = threadIdx.x;
    const int wg = tid >> 6;
    const int half = wg >> 2;
    const int w4 = wg & 3;
    const int lane = tid & 63;
    const int q = lane & 31;
    const int hi = lane >> 5;
    const int q0 = qt * 128 + w4 * 32;
    const int th = tid & 255;
    const float cexp = 0.18033688f;  // (1/sqrt(64)) * log2(e), folded into Q

    unsigned short* Kbuf = KV + half * 4096;
    unsigned short* Vbuf = KV + 8192 + half * 4096;

    // Q B-frags: col=q, k(dk) = ks*16 + hi*8 + j
    bf16x8 qf[4];
    {
        const float* qp = Q + ((size_t)(b * Sn + q0 + q)) * Dn + h * 64 + hi * 8;
#pragma unroll
        for (int ks = 0; ks < 4; ++ks) {
            float4 a0 = *(const float4*)(qp + ks * 16);
            float4 a1 = *(const float4*)(qp + ks * 16 + 4);
            union { unsigned u[4]; bf16x8 v; } f;
            f.u[0] = pk2(a0.x * cexp, a0.y * cexp);
            f.u[1] = pk2(a0.z * cexp, a0.w * cexp);
            f.u[2] = pk2(a1.x * cexp, a1.y * cexp);
            f.u[3] = pk2(a1.z * cexp, a1.w * cexp);
            qf[ks] = f.v;
        }
    }

    f32x16 zf;
#pragma unroll
    for (int r = 0; r < 16; ++r) zf[r] = 0.f;
    f32x16 oacc[2];
    oacc[0] = zf; oacc[1] = zf;
    float l_ = 0.f;

    const size_t tbase = ((size_t)bh * 64 + half * 32) * 4096;
    const unsigned short* kg = Kb + tbase;
    const unsigned short* vg = Vb + tbase;

    for (int it = 0; it < 32; ++it) {
        __syncthreads();
        {
            const unsigned short* ks_ = kg + (size_t)it * 4096;
            const unsigned short* vs_ = vg + (size_t)it * 4096;
            uint4 k0v = *(const uint4*)(ks_ + th * 8);
            uint4 k1v = *(const uint4*)(ks_ + 2048 + th * 8);
            uint4 v0v = *(const uint4*)(vs_ + th * 8);
            uint4 v1v = *(const uint4*)(vs_ + 2048 + th * 8);
            *(uint4*)&Kbuf[th * 8] = k0v;
            *(uint4*)&Kbuf[2048 + th * 8] = k1v;
            *(uint4*)&Vbuf[th * 8] = v0v;
            *(uint4*)&Vbuf[2048 + th * 8] = v1v;
        }
        __syncthreads();

#pragma unroll
        for (int t = 0; t < 2; ++t) {
            // S^T tile t = K(tile t) . Q^T, first MFMA consumes hoisted zero
            bf16x8 ka = *(const bf16x8*)&Kbuf[(t * 4 + 0) * 512 + lane * 8];
            f32x16 sa = __builtin_amdgcn_mfma_f32_32x32x16_bf16(ka, qf[0], zf, 0, 0, 0);
#pragma unroll
            for (int ks = 1; ks < 4; ++ks) {
                ka = *(const bf16x8*)&Kbuf[(t * 4 + ks) * 512 + lane * 8];
                sa = __builtin_amdgcn_mfma_f32_32x32x16_bf16(ka, qf[ks], sa, 0, 0, 0);
            }
            // p = exp2(s); lane-local l
            float e[16];
            float s0 = 0.f, s1 = 0.f;
#pragma unroll
            for (int r = 0; r < 16; r += 2) {
                e[r] = __builtin_amdgcn_exp2f(sa[r]);
                e[r + 1] = __builtin_amdgcn_exp2f(sa[r + 1]);
                s0 += e[r]; s1 += e[r + 1];
            }
            l_ += s0 + s1;
            // O^T += V^T . P^T, P B-frags in-register
#pragma unroll
            for (int k2 = 0; k2 < 2; ++k2) {
                unsigned g0x = pk2(e[8 * k2 + 0], e[8 * k2 + 1]);
                unsigned g0y = pk2(e[8 * k2 + 2], e[8 * k2 + 3]);
                unsigned g1x = pk2(e[8 * k2 + 4], e[8 * k2 + 5]);
                unsigned g1y = pk2(e[8 * k2 + 6], e[8 * k2 + 7]);
                bf16x8 pb = xchg2(g0x, g0y, g1x, g1y, hi);
                const int kp = t * 2 + k2;
                bf16x8 va0 = *(const bf16x8*)&Vbuf[(0 * 4 + kp) * 512 + lane * 8];
                bf16x8 va1 = *(const bf16x8*)&Vbuf[(1 * 4 + kp) * 512 + lane * 8];
                oacc[0] = __builtin_amdgcn_mfma_f32_32x32x16_bf16(va0, pb, oacc[0], 0, 0, 0);
                oacc[1] = __builtin_amdgcn_mfma_f32_32x32x16_bf16(va1, pb, oacc[1], 0, 0, 0);
            }
        }
    }

    // pair reduction through LDS (reuse KV as 4 x 2048 floats), then epilogue by half 0
    __syncthreads();
    float* rp = (float*)KV + w4 * 2048;
    if (half) {
#pragma unroll
        for (int g = 0; g < 8; ++g) {
            float4 v;
            v.x = oacc[g >> 2][(g & 3) * 4 + 0];
            v.y = oacc[g >> 2][(g & 3) * 4 + 1];
            v.z = oacc[g >> 2][(g & 3) * 4 + 2];
            v.w = oacc[g >> 2][(g & 3) * 4 + 3];
            *(float4*)&rp[g * 256 + lane * 4] = v;
        }
        Lsh[w4][lane] = l_;
    }
    __syncthreads();
    if (!half) {
#pragma unroll
        for (int g = 0; g < 8; ++g) {
            float4 v = *(const float4*)&rp[g * 256 + lane * 4];
            oacc[g >> 2][(g & 3) * 4 + 0] += v.x;
            oacc[g >> 2][(g & 3) * 4 + 1] += v.y;
            oacc[g >> 2][(g & 3) * 4 + 2] += v.z;
            oacc[g >> 2][(g & 3) * 4 + 3] += v.w;
        }
        l_ += Lsh[w4][lane];
        l_ += __shfl_xor(l_, 32);
        const float li = 1.f / l_;
        const int gm = b * 128 + qt * 4 + w4;
#pragma unroll
        for (int ksg = 0; ksg < 4; ++ksg) {
            const int dt = ksg >> 1, k2 = ksg & 1;
            unsigned g0x = pk2(oacc[dt][8 * k2 + 0] * li, oacc[dt][8 * k2 + 1] * li);
            unsigned g0y = pk2(oacc[dt][8 * k2 + 2] * li, oacc[dt][8 * k2 + 3] * li);
            unsigned g1x = pk2(oacc[dt][8 * k2 + 4] * li, oacc[dt][8 * k2 + 5] * li);
            unsigned g1y = pk2(oacc[dt][8 * k2 + 6] * li, oacc[dt][8 * k2 + 7] * li);
            bf16x8 frag = xchg2(g0x, g0y, g1x, g1y, hi);
            union { bf16x8 v; uint4 u; } fu; fu.v = frag;
            *(uint4*)&ObA[((size_t)(gm * 32 + h * 4 + ksg) * 64 + lane) * 8] = fu.u;
        }
    }
}

// ---------- projection GEMM: out = A @ W + b (A,W fragment-ordered bf16) ----------
// grid (64 mt of 128 rows, 8 nt of 64 cols), block 256 (4 waves, 32 rows each).
__global__ __launch_bounds__(256) void proj_kernel(
    const unsigned short* __restrict__ ObA,  // [256][32][64][8]
    const unsigned short* __restrict__ Wb,   // [16][32][64][8]
    const float* __restrict__ bias,
    float* __restrict__ out) {
    __shared__ __align__(16) unsigned short Ash[8192];
    __shared__ __align__(16) unsigned short Wsh[4096];

    const int mt = blockIdx.x;
    const int nt = blockIdx.y;
    const int tid = threadIdx.x;
    const int w = tid >> 6;
    const int lane = tid & 63;
    const int q = lane & 31;
    const int hi = lane >> 5;

    f32x16 acc[2];
#pragma unroll
    for (int t = 0; t < 2; ++t)
#pragma unroll
        for (int r = 0; r < 16; ++r) acc[t][r] = 0.f;

    for (int kt = 0; kt < 8; ++kt) {
        __syncthreads();
#pragma unroll
        for (int i = 0; i < 4; ++i) {
            int ci = (tid >> 6) + i * 4;     // 0..15
            int ml = ci >> 2, ksl = ci & 3;
            *(uint4*)&Ash[ci * 512 + lane * 8] =
                *(const uint4*)(ObA + (((size_t)(mt * 4 + ml) * 32 + kt * 4 + ksl) * 64 + lane) * 8);
        }
#pragma unroll
        for (int i = 0; i < 2; ++i) {
            int ci = (tid >> 6) + i * 4;     // 0..7
            int ntl = ci >> 2, ksl = ci & 3;
            *(uint4*)&Wsh[ci * 512 + lane * 8] =
                *(const uint4*)(Wb + (((size_t)(nt * 2 + ntl) * 32 + kt * 4 + ksl) * 64 + lane) * 8);
        }
        __syncthreads();

#pragma unroll
        for (int ks = 0; ks < 4; ++ks) {
            bf16x8 a  = *(const bf16x8*)&Ash[(w * 4 + ks) * 512 + lane * 8];
            bf16x8 b0 = *(const bf16x8*)&Wsh[(0 * 4 + ks) * 512 + lane * 8];
            bf16x8 b1 = *(const bf16x8*)&Wsh[(4 + ks) * 512 + lane * 8];
            acc[0] = __builtin_amdgcn_mfma_f32_32x32x16_bf16(a, b0, acc[0], 0, 0, 0);
            acc[1] = __builtin_amdgcn_mfma_f32_32x32x16_bf16(a, b1, acc[1], 0, 0, 0);
        }
    }

#pragma unroll
    for (int ntl = 0; ntl < 2; ++ntl) {
        int col = nt * 64 + ntl * 32 + q;
        float bv = bias[col];
#pragma unroll
        for (int reg = 0; reg < 16; ++reg) {
            int row = mt * 128 + w * 32 + (reg & 3) + 8 * (reg >> 2) + 4 * hi;
            out[(size_t)row * Dn + col] = acc[ntl][reg] + bv;
        }
    }
}

extern "C" void kernel_launch(void* const* d_in, const int* in_sizes, int n_in,
                              void* d_out, int out_size, void* d_ws, size_t ws_size,
                              hipStream_t stream) {
    const float* Q = (const float*)d_in[0];
    const float* K = (const float*)d_in[1];
    const float* V = (const float*)d_in[2];
    const float* W = (const float*)d_in[3];
    const float* bo = (const float*)d_in[4];
    float* out = (float*)d_out;

    char* ws = (char*)d_ws;
    unsigned short* Kb  = (unsigned short*)(ws);                 // 8 MB
    unsigned short* Vb  = (unsigned short*)(ws + 8388608);       // 8 MB
    unsigned short* Wb  = (unsigned short*)(ws + 16777216);      // 512 KB
    unsigned short* ObA = (unsigned short*)(ws + 17301504);      // 8 MB

    prep_kernel<<<2176, 256, 0, stream>>>(K, V, W, Kb, Vb, Wb);
    attn_kernel<<<dim3(32, 16), 512, 0, stream>>>(Q, Kb, Vb, ObA);
    proj_kernel<<<dim3(64, 8), 256, 0, stream>>>(ObA, Wb, bo, out);
}

// Round 6
// 190.581 us; speedup vs baseline: 1.1450x; 1.0151x over previous
//
#include <hip/hip_runtime.h>
#include <hip/hip_bf16.h>

#define Bn 2
#define Sn 4096
#define Dn 512
#define Hn 8

typedef _Float16 f16x8 __attribute__((ext_vector_type(8)));
typedef _Float16 f16x4 __attribute__((ext_vector_type(4)));
typedef __fp16 fp16x2 __attribute__((ext_vector_type(2)));
typedef float f32x16 __attribute__((ext_vector_type(16)));

// pack two f32 -> two f16 in one dword (v_cvt_pkrtz_f16_f32, 1 VALU op)
static __device__ __forceinline__ unsigned pkh(float a, float b) {
    union { fp16x2 h; unsigned u; } r;
    r.h = __builtin_amdgcn_cvt_pkrtz(a, b);
    return r.u;
}

// C-layout group pair -> A/B-fragment (K=16 shapes) via lane^32 exchange.
static __device__ __forceinline__ f16x8 xchg2(unsigned g0x, unsigned g0y,
                                              unsigned g1x, unsigned g1y, int hi) {
    int sx = hi ? (int)g0x : (int)g1x;
    int sy = hi ? (int)g0y : (int)g1y;
    int rx = __shfl_xor(sx, 32);
    int ry = __shfl_xor(sy, 32);
    unsigned ox = hi ? g1x : g0x;
    unsigned oy = hi ? g1y : g0y;
    union { unsigned u[4]; f16x8 v; } f;
    f.u[0] = hi ? (unsigned)rx : ox;
    f.u[1] = hi ? (unsigned)ry : oy;
    f.u[2] = hi ? ox : (unsigned)rx;
    f.u[3] = hi ? oy : (unsigned)ry;
    return f.v;
}

// ---------- unified prepass: K,V,W fp32 -> fragment-ordered f16 ----------
// blocks 0..1023: K -> Kb [bh][kt64][f=ktile*4+ks][lane][8]   (QK A-frags, K=16)
// blocks 1024..2047: V -> Vb [bh][kt64][fv=dt*8+ks7][lane][4] (PV A-frags, K=8, V^T)
// blocks 2048..2175: W -> Wb [ntile16][kstep32][lane][8]      (proj B-frags, W^T)
__global__ __launch_bounds__(256) void prep_kernel(
    const float* __restrict__ K, const float* __restrict__ V, const float* __restrict__ W,
    unsigned short* __restrict__ Kb, unsigned short* __restrict__ Vb,
    unsigned short* __restrict__ Wb) {
    const int vb = blockIdx.x;
    const int tid = threadIdx.x;
    if (vb < 1024) {
        const int kt = vb & 63, bh = vb >> 6;
        const int b = bh >> 3, h = bh & 7;
        unsigned short* dst = Kb + ((size_t)bh * 64 + kt) * 4096;
#pragma unroll
        for (int i = 0; i < 2; ++i) {
            int c = tid + i * 256;
            int f = c >> 6, ln = c & 63;
            int ktile = f >> 2, ks = f & 3;
            int row = ktile * 32 + (ln & 31);
            int dk = ks * 16 + (ln >> 5) * 8;
            const float* src = K + ((size_t)(b * Sn + kt * 64 + row)) * Dn + h * 64 + dk;
            float4 a0 = *(const float4*)src;
            float4 a1 = *(const float4*)(src + 4);
            uint4 o;
            o.x = pkh(a0.x, a0.y); o.y = pkh(a0.z, a0.w);
            o.z = pkh(a1.x, a1.y); o.w = pkh(a1.z, a1.w);
            *(uint4*)(dst + c * 8) = o;
        }
    } else if (vb < 2048) {
        const int u = vb - 1024;
        const int kt = u & 63, bh = u >> 6;
        const int b = bh >> 3, h = bh & 7;
        unsigned short* dst = Vb + ((size_t)bh * 64 + kt) * 4096;
#pragma unroll
        for (int i = 0; i < 4; ++i) {
            int c = tid + i * 256;              // 0..1023
            int f = c >> 6, ln = c & 63;        // frag, lane
            int dt = f >> 3, ks7 = f & 7;
            int dk = dt * 32 + (ln & 31);
            int key0 = ks7 * 8 + (ln >> 5) * 4;
            const float* src = V + ((size_t)(b * Sn + kt * 64 + key0)) * Dn + h * 64 + dk;
            uint2 o;
            o.x = pkh(src[0 * Dn], src[1 * Dn]);
            o.y = pkh(src[2 * Dn], src[3 * Dn]);
            *(uint2*)(dst + c * 4) = o;
        }
    } else {
        int c = (vb - 2048) * 256 + tid;   // 0..32767
        int ln = c & 63, f = c >> 6;
        int ntile = f >> 5, ks = f & 31;
        int n = ntile * 32 + (ln & 31);
        int k0 = ks * 16 + (ln >> 5) * 8;
        uint4 o;
        o.x = pkh(W[(size_t)(k0 + 0) * Dn + n], W[(size_t)(k0 + 1) * Dn + n]);
        o.y = pkh(W[(size_t)(k0 + 2) * Dn + n], W[(size_t)(k0 + 3) * Dn + n]);
        o.z = pkh(W[(size_t)(k0 + 4) * Dn + n], W[(size_t)(k0 + 5) * Dn + n]);
        o.w = pkh(W[(size_t)(k0 + 6) * Dn + n], W[(size_t)(k0 + 7) * Dn + n]);
        *(uint4*)(Wb + c * 8) = o;
    }
}

// ---------- flash attention: f16, K=8 PV (no in-loop transpose), key-split x2 ----------
// block 512 thr = 8 waves: waves 0-3 keys 0..2047, waves 4-7 keys 2048..4095;
// wave pair (w4, w4+4) shares q-tile; pair-reduce via LDS at end.
__global__ __launch_bounds__(512, 4) void attn_kernel(
    const float* __restrict__ Q,
    const unsigned short* __restrict__ Kb,
    const unsigned short* __restrict__ Vb,
    unsigned short* __restrict__ ObA) {   // [gmtile 256][ksg 32][lane 64][8]
    __shared__ __align__(16) unsigned short KV[16384];  // 2x K(8KB) + 2x V(8KB)
    __shared__ float Lsh[4][64];

    const int qt = blockIdx.x;
    const int bh = blockIdx.y;
    const int b = bh >> 3, h = bh & 7;
    const int tid = threadIdx.x;
    const int wg = tid >> 6;
    const int half = wg >> 2;
    const int w4 = wg & 3;
    const int lane = tid & 63;
    const int q = lane & 31;
    const int hi = lane >> 5;
    const int q0 = qt * 128 + w4 * 32;
    const int th = tid & 255;
    const float cexp = 0.18033688f;  // (1/sqrt(64)) * log2(e), folded into Q

    unsigned short* Kbuf = KV + half * 4096;
    unsigned short* Vbuf = KV + 8192 + half * 4096;

    // Q B-frags (K=16): col=q, k(dk) = ks*16 + hi*8 + j
    f16x8 qf[4];
    {
        const float* qp = Q + ((size_t)(b * Sn + q0 + q)) * Dn + h * 64 + hi * 8;
#pragma unroll
        for (int ks = 0; ks < 4; ++ks) {
            float4 a0 = *(const float4*)(qp + ks * 16);
            float4 a1 = *(const float4*)(qp + ks * 16 + 4);
            union { unsigned u[4]; f16x8 v; } f;
            f.u[0] = pkh(a0.x * cexp, a0.y * cexp);
            f.u[1] = pkh(a0.z * cexp, a0.w * cexp);
            f.u[2] = pkh(a1.x * cexp, a1.y * cexp);
            f.u[3] = pkh(a1.z * cexp, a1.w * cexp);
            qf[ks] = f.v;
        }
    }

    f32x16 zf;
#pragma unroll
    for (int r = 0; r < 16; ++r) zf[r] = 0.f;
    f32x16 oacc[2];
    oacc[0] = zf; oacc[1] = zf;
    float l_ = 0.f;

    const size_t tbase = ((size_t)bh * 64 + half * 32) * 4096;
    const unsigned short* kg = Kb + tbase;
    const unsigned short* vg = Vb + tbase;

    // preload tile 0
    uint4 gk0 = *(const uint4*)(kg + th * 16);
    uint4 gk1 = *(const uint4*)(kg + th * 16 + 8);
    uint4 gv0 = *(const uint4*)(vg + th * 16);
    uint4 gv1 = *(const uint4*)(vg + th * 16 + 8);

    for (int it = 0; it < 32; ++it) {
        __syncthreads();
        *(uint4*)&Kbuf[th * 16] = gk0;
        *(uint4*)&Kbuf[th * 16 + 8] = gk1;
        *(uint4*)&Vbuf[th * 16] = gv0;
        *(uint4*)&Vbuf[th * 16 + 8] = gv1;
        __syncthreads();
        if (it < 31) {  // preload next tile while computing this one
            const unsigned short* ks_ = kg + (size_t)(it + 1) * 4096;
            const unsigned short* vs_ = vg + (size_t)(it + 1) * 4096;
            gk0 = *(const uint4*)(ks_ + th * 16);
            gk1 = *(const uint4*)(ks_ + th * 16 + 8);
            gv0 = *(const uint4*)(vs_ + th * 16);
            gv1 = *(const uint4*)(vs_ + th * 16 + 8);
        }

#pragma unroll
        for (int t = 0; t < 2; ++t) {
            // S^T tile t = K(tile t) . Q^T  (K=16 f16 MFMA, hoisted-zero C)
            f16x8 ka = *(const f16x8*)&Kbuf[(t * 4 + 0) * 512 + lane * 8];
            f32x16 sa = __builtin_amdgcn_mfma_f32_32x32x16_f16(ka, qf[0], zf, 0, 0, 0);
#pragma unroll
            for (int ks = 1; ks < 4; ++ks) {
                ka = *(const f16x8*)&Kbuf[(t * 4 + ks) * 512 + lane * 8];
                sa = __builtin_amdgcn_mfma_f32_32x32x16_f16(ka, qf[ks], sa, 0, 0, 0);
            }
            // p = exp2(s); lane-local l
            float e[16];
            float s0 = 0.f, s1 = 0.f;
#pragma unroll
            for (int r = 0; r < 16; r += 2) {
                e[r] = __builtin_amdgcn_exp2f(sa[r]);
                e[r + 1] = __builtin_amdgcn_exp2f(sa[r + 1]);
                s0 += e[r]; s1 += e[r + 1];
            }
            l_ += s0 + s1;
            // O^T += V^T . P^T via K=8 MFMA: C-layout reg group IS the B-frag.
#pragma unroll
            for (int s = 0; s < 4; ++s) {
                union { unsigned u[2]; f16x4 v; } pb;
                pb.u[0] = pkh(e[4 * s + 0], e[4 * s + 1]);
                pb.u[1] = pkh(e[4 * s + 2], e[4 * s + 3]);
                f16x4 va0 = *(const f16x4*)&Vbuf[(0 * 8 + t * 4 + s) * 256 + lane * 4];
                f16x4 va1 = *(const f16x4*)&Vbuf[(1 * 8 + t * 4 + s) * 256 + lane * 4];
                oacc[0] = __builtin_amdgcn_mfma_f32_32x32x8f16(va0, pb.v, oacc[0], 0, 0, 0);
                oacc[1] = __builtin_amdgcn_mfma_f32_32x32x8f16(va1, pb.v, oacc[1], 0, 0, 0);
            }
        }
    }

    // pair reduction through LDS (reuse KV as 4 x 2048 floats), epilogue by half 0
    __syncthreads();
    float* rp = (float*)KV + w4 * 2048;
    if (half) {
#pragma unroll
        for (int g = 0; g < 8; ++g) {
            float4 v;
            v.x = oacc[g >> 2][(g & 3) * 4 + 0];
            v.y = oacc[g >> 2][(g & 3) * 4 + 1];
            v.z = oacc[g >> 2][(g & 3) * 4 + 2];
            v.w = oacc[g >> 2][(g & 3) * 4 + 3];
            *(float4*)&rp[g * 256 + lane * 4] = v;
        }
        Lsh[w4][lane] = l_;
    }
    __syncthreads();
    if (!half) {
#pragma unroll
        for (int g = 0; g < 8; ++g) {
            float4 v = *(const float4*)&rp[g * 256 + lane * 4];
            oacc[g >> 2][(g & 3) * 4 + 0] += v.x;
            oacc[g >> 2][(g & 3) * 4 + 1] += v.y;
            oacc[g >> 2][(g & 3) * 4 + 2] += v.z;
            oacc[g >> 2][(g & 3) * 4 + 3] += v.w;
        }
        l_ += Lsh[w4][lane];
        l_ += __shfl_xor(l_, 32);
        const float li = 1.f / l_;
        const int gm = b * 128 + qt * 4 + w4;
#pragma unroll
        for (int ksg = 0; ksg < 4; ++ksg) {
            const int dt = ksg >> 1, k2 = ksg & 1;
            unsigned g0x = pkh(oacc[dt][8 * k2 + 0] * li, oacc[dt][8 * k2 + 1] * li);
            unsigned g0y = pkh(oacc[dt][8 * k2 + 2] * li, oacc[dt][8 * k2 + 3] * li);
            unsigned g1x = pkh(oacc[dt][8 * k2 + 4] * li, oacc[dt][8 * k2 + 5] * li);
            unsigned g1y = pkh(oacc[dt][8 * k2 + 6] * li, oacc[dt][8 * k2 + 7] * li);
            f16x8 frag = xchg2(g0x, g0y, g1x, g1y, hi);
            union { f16x8 v; uint4 u; } fu; fu.v = frag;
            *(uint4*)&ObA[((size_t)(gm * 32 + h * 4 + ksg) * 64 + lane) * 8] = fu.u;
        }
    }
}

// ---------- projection GEMM: out = A @ W + b (A,W fragment-ordered f16) ----------
// grid (64 mt of 128 rows, 8 nt of 64 cols), block 256 (4 waves, 32 rows each).
__global__ __launch_bounds__(256) void proj_kernel(
    const unsigned short* __restrict__ ObA,  // [256][32][64][8]
    const unsigned short* __restrict__ Wb,   // [16][32][64][8]
    const float* __restrict__ bias,
    float* __restrict__ out) {
    __shared__ __align__(16) unsigned short Ash[8192];
    __shared__ __align__(16) unsigned short Wsh[4096];

    const int mt = blockIdx.x;
    const int nt = blockIdx.y;
    const int tid = threadIdx.x;
    const int w = tid >> 6;
    const int lane = tid & 63;
    const int q = lane & 31;
    const int hi = lane >> 5;

    f32x16 acc[2];
#pragma unroll
    for (int t = 0; t < 2; ++t)
#pragma unroll
        for (int r = 0; r < 16; ++r) acc[t][r] = 0.f;

    for (int kt = 0; kt < 8; ++kt) {
        __syncthreads();
#pragma unroll
        for (int i = 0; i < 4; ++i) {
            int ci = (tid >> 6) + i * 4;     // 0..15
            int ml = ci >> 2, ksl = ci & 3;
            *(uint4*)&Ash[ci * 512 + lane * 8] =
                *(const uint4*)(ObA + (((size_t)(mt * 4 + ml) * 32 + kt * 4 + ksl) * 64 + lane) * 8);
        }
#pragma unroll
        for (int i = 0; i < 2; ++i) {
            int ci = (tid >> 6) + i * 4;     // 0..7
            int ntl = ci >> 2, ksl = ci & 3;
            *(uint4*)&Wsh[ci * 512 + lane * 8] =
                *(const uint4*)(Wb + (((size_t)(nt * 2 + ntl) * 32 + kt * 4 + ksl) * 64 + lane) * 8);
        }
        __syncthreads();

#pragma unroll
        for (int ks = 0; ks < 4; ++ks) {
            f16x8 a  = *(const f16x8*)&Ash[(w * 4 + ks) * 512 + lane * 8];
            f16x8 b0 = *(const f16x8*)&Wsh[(0 * 4 + ks) * 512 + lane * 8];
            f16x8 b1 = *(const f16x8*)&Wsh[(4 + ks) * 512 + lane * 8];
            acc[0] = __builtin_amdgcn_mfma_f32_32x32x16_f16(a, b0, acc[0], 0, 0, 0);
            acc[1] = __builtin_amdgcn_mfma_f32_32x32x16_f16(a, b1, acc[1], 0, 0, 0);
        }
    }

#pragma unroll
    for (int ntl = 0; ntl < 2; ++ntl) {
        int col = nt * 64 + ntl * 32 + q;
        float bv = bias[col];
#pragma unroll
        for (int reg = 0; reg < 16; ++reg) {
            int row = mt * 128 + w * 32 + (reg & 3) + 8 * (reg >> 2) + 4 * hi;
            out[(size_t)row * Dn + col] = acc[ntl][reg] + bv;
        }
    }
}

extern "C" void kernel_launch(void* const* d_in, const int* in_sizes, int n_in,
                              void* d_out, int out_size, void* d_ws, size_t ws_size,
                              hipStream_t stream) {
    const float* Q = (const float*)d_in[0];
    const float* K = (const float*)d_in[1];
    const float* V = (const float*)d_in[2];
    const float* W = (const float*)d_in[3];
    const float* bo = (const float*)d_in[4];
    float* out = (float*)d_out;

    char* ws = (char*)d_ws;
    unsigned short* Kb  = (unsigned short*)(ws);                 // 8 MB
    unsigned short* Vb  = (unsigned short*)(ws + 8388608);       // 8 MB
    unsigned short* Wb  = (unsigned short*)(ws + 16777216);      // 512 KB
    unsigned short* ObA = (unsigned short*)(ws + 17301504);      // 8 MB

    prep_kernel<<<2176, 256, 0, stream>>>(K, V, W, Kb, Vb, Wb);
    attn_kernel<<<dim3(32, 16), 512, 0, stream>>>(Q, Kb, Vb, ObA);
    proj_kernel<<<dim3(64, 8), 256, 0, stream>>>(ObA, Wb, bo, out);
}

// Round 7
// 189.330 us; speedup vs baseline: 1.1526x; 1.0066x over previous
//
#include <hip/hip_runtime.h>
#include <hip/hip_bf16.h>

#define Bn 2
#define Sn 4096
#define Dn 512
#define Hn 8

typedef _Float16 f16x8 __attribute__((ext_vector_type(8)));
typedef __fp16 fp16x2 __attribute__((ext_vector_type(2)));
typedef float f32x16 __attribute__((ext_vector_type(16)));

// pack two f32 -> two f16 in one dword (v_cvt_pkrtz_f16_f32, 1 VALU op)
static __device__ __forceinline__ unsigned pkh(float a, float b) {
    union { fp16x2 h; unsigned u; } r;
    r.h = __builtin_amdgcn_cvt_pkrtz(a, b);
    return r.u;
}

// C-layout group pair -> A/B-fragment (K=16 shapes) via lane^32 exchange.
static __device__ __forceinline__ f16x8 xchg2(unsigned g0x, unsigned g0y,
                                              unsigned g1x, unsigned g1y, int hi) {
    int sx = hi ? (int)g0x : (int)g1x;
    int sy = hi ? (int)g0y : (int)g1y;
    int rx = __shfl_xor(sx, 32);
    int ry = __shfl_xor(sy, 32);
    unsigned ox = hi ? g1x : g0x;
    unsigned oy = hi ? g1y : g0y;
    union { unsigned u[4]; f16x8 v; } f;
    f.u[0] = hi ? (unsigned)rx : ox;
    f.u[1] = hi ? (unsigned)ry : oy;
    f.u[2] = hi ? ox : (unsigned)rx;
    f.u[3] = hi ? oy : (unsigned)ry;
    return f.v;
}

// ---------- unified prepass: K,V,W fp32 -> fragment-ordered f16 ----------
// blocks 0..1023: K -> Kb [bh][kt64][f=ktile*4+ks][lane][8]   (QK A-frags, K=16)
// blocks 1024..2047: V -> Vb [bh][kt64][f=dt*4+ks][lane][8]   (PV A-frags, K=16, V^T)
// blocks 2048..2175: W -> Wb [ntile16][kstep32][lane][8]      (proj B-frags, W^T)
__global__ __launch_bounds__(256) void prep_kernel(
    const float* __restrict__ K, const float* __restrict__ V, const float* __restrict__ W,
    unsigned short* __restrict__ Kb, unsigned short* __restrict__ Vb,
    unsigned short* __restrict__ Wb) {
    const int vb = blockIdx.x;
    const int tid = threadIdx.x;
    if (vb < 1024) {
        const int kt = vb & 63, bh = vb >> 6;
        const int b = bh >> 3, h = bh & 7;
        unsigned short* dst = Kb + ((size_t)bh * 64 + kt) * 4096;
#pragma unroll
        for (int i = 0; i < 2; ++i) {
            int c = tid + i * 256;
            int f = c >> 6, ln = c & 63;
            int ktile = f >> 2, ks = f & 3;
            int row = ktile * 32 + (ln & 31);
            int dk = ks * 16 + (ln >> 5) * 8;
            const float* src = K + ((size_t)(b * Sn + kt * 64 + row)) * Dn + h * 64 + dk;
            float4 a0 = *(const float4*)src;
            float4 a1 = *(const float4*)(src + 4);
            uint4 o;
            o.x = pkh(a0.x, a0.y); o.y = pkh(a0.z, a0.w);
            o.z = pkh(a1.x, a1.y); o.w = pkh(a1.z, a1.w);
            *(uint4*)(dst + c * 8) = o;
        }
    } else if (vb < 2048) {
        const int u = vb - 1024;
        const int kt = u & 63, bh = u >> 6;
        const int b = bh >> 3, h = bh & 7;
        unsigned short* dst = Vb + ((size_t)bh * 64 + kt) * 4096;
#pragma unroll
        for (int i = 0; i < 2; ++i) {
            int c = tid + i * 256;              // 0..511
            int f = c >> 6, ln = c & 63;        // frag, lane
            int dt = f >> 2, ks = f & 3;
            int dk = dt * 32 + (ln & 31);
            int key0 = ks * 16 + (ln >> 5) * 8;
            const float* src = V + ((size_t)(b * Sn + kt * 64 + key0)) * Dn + h * 64 + dk;
            uint4 o;
            o.x = pkh(src[0 * Dn], src[1 * Dn]);
            o.y = pkh(src[2 * Dn], src[3 * Dn]);
            o.z = pkh(src[4 * Dn], src[5 * Dn]);
            o.w = pkh(src[6 * Dn], src[7 * Dn]);
            *(uint4*)(dst + c * 8) = o;
        }
    } else {
        int c = (vb - 2048) * 256 + tid;   // 0..32767
        int ln = c & 63, f = c >> 6;
        int ntile = f >> 5, ks = f & 31;
        int n = ntile * 32 + (ln & 31);
        int k0 = ks * 16 + (ln >> 5) * 8;
        uint4 o;
        o.x = pkh(W[(size_t)(k0 + 0) * Dn + n], W[(size_t)(k0 + 1) * Dn + n]);
        o.y = pkh(W[(size_t)(k0 + 2) * Dn + n], W[(size_t)(k0 + 3) * Dn + n]);
        o.z = pkh(W[(size_t)(k0 + 4) * Dn + n], W[(size_t)(k0 + 5) * Dn + n]);
        o.w = pkh(W[(size_t)(k0 + 6) * Dn + n], W[(size_t)(k0 + 7) * Dn + n]);
        *(uint4*)(Wb + c * 8) = o;
    }
}

// ---------- flash attention: f16, K=16 PV (in-register xchg transpose), key-split x2 ----------
// block 512 thr = 8 waves: waves 0-3 keys 0..2047, waves 4-7 keys 2048..4095;
// wave pair (w4, w4+4) shares q-tile; pair-reduce via LDS at end.
__global__ __launch_bounds__(512, 4) void attn_kernel(
    const float* __restrict__ Q,
    const unsigned short* __restrict__ Kb,
    const unsigned short* __restrict__ Vb,
    unsigned short* __restrict__ ObA) {   // [gmtile 256][ksg 32][lane 64][8]
    __shared__ __align__(16) unsigned short KV[16384];  // 2x K(8KB) + 2x V(8KB)
    __shared__ float Lsh[4][64];

    const int qt = blockIdx.x;
    const int bh = blockIdx.y;
    const int b = bh >> 3, h = bh & 7;
    const int tid = threadIdx.x;
    const int wg = tid >> 6;
    const int half = wg >> 2;
    const int w4 = wg & 3;
    const int lane = tid & 63;
    const int q = lane & 31;
    const int hi = lane >> 5;
    const int q0 = qt * 128 + w4 * 32;
    const int th = tid & 255;
    const float cexp = 0.18033688f;  // (1/sqrt(64)) * log2(e), folded into Q

    unsigned short* Kbuf = KV + half * 4096;
    unsigned short* Vbuf = KV + 8192 + half * 4096;

    // Q B-frags (K=16): col=q, k(dk) = ks*16 + hi*8 + j
    f16x8 qf[4];
    {
        const float* qp = Q + ((size_t)(b * Sn + q0 + q)) * Dn + h * 64 + hi * 8;
#pragma unroll
        for (int ks = 0; ks < 4; ++ks) {
            float4 a0 = *(const float4*)(qp + ks * 16);
            float4 a1 = *(const float4*)(qp + ks * 16 + 4);
            union { unsigned u[4]; f16x8 v; } f;
            f.u[0] = pkh(a0.x * cexp, a0.y * cexp);
            f.u[1] = pkh(a0.z * cexp, a0.w * cexp);
            f.u[2] = pkh(a1.x * cexp, a1.y * cexp);
            f.u[3] = pkh(a1.z * cexp, a1.w * cexp);
            qf[ks] = f.v;
        }
    }

    f32x16 zf;
#pragma unroll
    for (int r = 0; r < 16; ++r) zf[r] = 0.f;
    f32x16 oacc[2];
    oacc[0] = zf; oacc[1] = zf;
    float l_ = 0.f;

    const size_t tbase = ((size_t)bh * 64 + half * 32) * 4096;
    const unsigned short* kg = Kb + tbase;
    const unsigned short* vg = Vb + tbase;

    // preload tile 0
    uint4 gk0 = *(const uint4*)(kg + th * 16);
    uint4 gk1 = *(const uint4*)(kg + th * 16 + 8);
    uint4 gv0 = *(const uint4*)(vg + th * 16);
    uint4 gv1 = *(const uint4*)(vg + th * 16 + 8);

    for (int it = 0; it < 32; ++it) {
        __syncthreads();
        *(uint4*)&Kbuf[th * 16] = gk0;
        *(uint4*)&Kbuf[th * 16 + 8] = gk1;
        *(uint4*)&Vbuf[th * 16] = gv0;
        *(uint4*)&Vbuf[th * 16 + 8] = gv1;
        __syncthreads();
        if (it < 31) {  // preload next tile while computing this one
            const unsigned short* ks_ = kg + (size_t)(it + 1) * 4096;
            const unsigned short* vs_ = vg + (size_t)(it + 1) * 4096;
            gk0 = *(const uint4*)(ks_ + th * 16);
            gk1 = *(const uint4*)(ks_ + th * 16 + 8);
            gv0 = *(const uint4*)(vs_ + th * 16);
            gv1 = *(const uint4*)(vs_ + th * 16 + 8);
        }

#pragma unroll
        for (int t = 0; t < 2; ++t) {
            // S^T tile t = K(tile t) . Q^T  (K=16 f16 MFMA, hoisted-zero C)
            f16x8 ka = *(const f16x8*)&Kbuf[(t * 4 + 0) * 512 + lane * 8];
            f32x16 sa = __builtin_amdgcn_mfma_f32_32x32x16_f16(ka, qf[0], zf, 0, 0, 0);
#pragma unroll
            for (int ks = 1; ks < 4; ++ks) {
                ka = *(const f16x8*)&Kbuf[(t * 4 + ks) * 512 + lane * 8];
                sa = __builtin_amdgcn_mfma_f32_32x32x16_f16(ka, qf[ks], sa, 0, 0, 0);
            }
            // p = exp2(s); lane-local l
            float e[16];
            float s0 = 0.f, s1 = 0.f;
#pragma unroll
            for (int r = 0; r < 16; r += 2) {
                e[r] = __builtin_amdgcn_exp2f(sa[r]);
                e[r + 1] = __builtin_amdgcn_exp2f(sa[r + 1]);
                s0 += e[r]; s1 += e[r + 1];
            }
            l_ += s0 + s1;
            // O^T += V^T . P^T  (K=16: B-frag from C-groups via lane^32 exchange)
#pragma unroll
            for (int s2 = 0; s2 < 2; ++s2) {
                unsigned g0x = pkh(e[8 * s2 + 0], e[8 * s2 + 1]);
                unsigned g0y = pkh(e[8 * s2 + 2], e[8 * s2 + 3]);
                unsigned g1x = pkh(e[8 * s2 + 4], e[8 * s2 + 5]);
                unsigned g1y = pkh(e[8 * s2 + 6], e[8 * s2 + 7]);
                f16x8 pb = xchg2(g0x, g0y, g1x, g1y, hi);
                const int kp = t * 2 + s2;   // global ks index 0..3
                f16x8 va0 = *(const f16x8*)&Vbuf[(0 * 4 + kp) * 512 + lane * 8];
                f16x8 va1 = *(const f16x8*)&Vbuf[(1 * 4 + kp) * 512 + lane * 8];
                oacc[0] = __builtin_amdgcn_mfma_f32_32x32x16_f16(va0, pb, oacc[0], 0, 0, 0);
                oacc[1] = __builtin_amdgcn_mfma_f32_32x32x16_f16(va1, pb, oacc[1], 0, 0, 0);
            }
        }
    }

    // pair reduction through LDS (reuse KV as 4 x 2048 floats), epilogue by half 0
    __syncthreads();
    float* rp = (float*)KV + w4 * 2048;
    if (half) {
#pragma unroll
        for (int g = 0; g < 8; ++g) {
            float4 v;
            v.x = oacc[g >> 2][(g & 3) * 4 + 0];
            v.y = oacc[g >> 2][(g & 3) * 4 + 1];
            v.z = oacc[g >> 2][(g & 3) * 4 + 2];
            v.w = oacc[g >> 2][(g & 3) * 4 + 3];
            *(float4*)&rp[g * 256 + lane * 4] = v;
        }
        Lsh[w4][lane] = l_;
    }
    __syncthreads();
    if (!half) {
#pragma unroll
        for (int g = 0; g < 8; ++g) {
            float4 v = *(const float4*)&rp[g * 256 + lane * 4];
            oacc[g >> 2][(g & 3) * 4 + 0] += v.x;
            oacc[g >> 2][(g & 3) * 4 + 1] += v.y;
            oacc[g >> 2][(g & 3) * 4 + 2] += v.z;
            oacc[g >> 2][(g & 3) * 4 + 3] += v.w;
        }
        l_ += Lsh[w4][lane];
        l_ += __shfl_xor(l_, 32);
        const float li = 1.f / l_;
        const int gm = b * 128 + qt * 4 + w4;
#pragma unroll
        for (int ksg = 0; ksg < 4; ++ksg) {
            const int dt = ksg >> 1, k2 = ksg & 1;
            unsigned g0x = pkh(oacc[dt][8 * k2 + 0] * li, oacc[dt][8 * k2 + 1] * li);
            unsigned g0y = pkh(oacc[dt][8 * k2 + 2] * li, oacc[dt][8 * k2 + 3] * li);
            unsigned g1x = pkh(oacc[dt][8 * k2 + 4] * li, oacc[dt][8 * k2 + 5] * li);
            unsigned g1y = pkh(oacc[dt][8 * k2 + 6] * li, oacc[dt][8 * k2 + 7] * li);
            f16x8 frag = xchg2(g0x, g0y, g1x, g1y, hi);
            union { f16x8 v; uint4 u; } fu; fu.v = frag;
            *(uint4*)&ObA[((size_t)(gm * 32 + h * 4 + ksg) * 64 + lane) * 8] = fu.u;
        }
    }
}

// ---------- projection GEMM: out = A @ W + b (A,W fragment-ordered f16) ----------
// grid (64 mt of 128 rows, 8 nt of 64 cols), block 256 (4 waves, 32 rows each).
__global__ __launch_bounds__(256) void proj_kernel(
    const unsigned short* __restrict__ ObA,  // [256][32][64][8]
    const unsigned short* __restrict__ Wb,   // [16][32][64][8]
    const float* __restrict__ bias,
    float* __restrict__ out) {
    __shared__ __align__(16) unsigned short Ash[8192];
    __shared__ __align__(16) unsigned short Wsh[4096];

    const int mt = blockIdx.x;
    const int nt = blockIdx.y;
    const int tid = threadIdx.x;
    const int w = tid >> 6;
    const int lane = tid & 63;
    const int q = lane & 31;
    const int hi = lane >> 5;

    f32x16 acc[2];
#pragma unroll
    for (int t = 0; t < 2; ++t)
#pragma unroll
        for (int r = 0; r < 16; ++r) acc[t][r] = 0.f;

    for (int kt = 0; kt < 8; ++kt) {
        __syncthreads();
#pragma unroll
        for (int i = 0; i < 4; ++i) {
            int ci = (tid >> 6) + i * 4;     // 0..15
            int ml = ci >> 2, ksl = ci & 3;
            *(uint4*)&Ash[ci * 512 + lane * 8] =
                *(const uint4*)(ObA + (((size_t)(mt * 4 + ml) * 32 + kt * 4 + ksl) * 64 + lane) * 8);
        }
#pragma unroll
        for (int i = 0; i < 2; ++i) {
            int ci = (tid >> 6) + i * 4;     // 0..7
            int ntl = ci >> 2, ksl = ci & 3;
            *(uint4*)&Wsh[ci * 512 + lane * 8] =
                *(const uint4*)(Wb + (((size_t)(nt * 2 + ntl) * 32 + kt * 4 + ksl) * 64 + lane) * 8);
        }
        __syncthreads();

#pragma unroll
        for (int ks = 0; ks < 4; ++ks) {
            f16x8 a  = *(const f16x8*)&Ash[(w * 4 + ks) * 512 + lane * 8];
            f16x8 b0 = *(const f16x8*)&Wsh[(0 * 4 + ks) * 512 + lane * 8];
            f16x8 b1 = *(const f16x8*)&Wsh[(4 + ks) * 512 + lane * 8];
            acc[0] = __builtin_amdgcn_mfma_f32_32x32x16_f16(a, b0, acc[0], 0, 0, 0);
            acc[1] = __builtin_amdgcn_mfma_f32_32x32x16_f16(a, b1, acc[1], 0, 0, 0);
        }
    }

#pragma unroll
    for (int ntl = 0; ntl < 2; ++ntl) {
        int col = nt * 64 + ntl * 32 + q;
        float bv = bias[col];
#pragma unroll
        for (int reg = 0; reg < 16; ++reg) {
            int row = mt * 128 + w * 32 + (reg & 3) + 8 * (reg >> 2) + 4 * hi;
            out[(size_t)row * Dn + col] = acc[ntl][reg] + bv;
        }
    }
}

extern "C" void kernel_launch(void* const* d_in, const int* in_sizes, int n_in,
                              void* d_out, int out_size, void* d_ws, size_t ws_size,
                              hipStream_t stream) {
    const float* Q = (const float*)d_in[0];
    const float* K = (const float*)d_in[1];
    const float* V = (const float*)d_in[2];
    const float* W = (const float*)d_in[3];
    const float* bo = (const float*)d_in[4];
    float* out = (float*)d_out;

    char* ws = (char*)d_ws;
    unsigned short* Kb  = (unsigned short*)(ws);                 // 8 MB
    unsigned short* Vb  = (unsigned short*)(ws + 8388608);       // 8 MB
    unsigned short* Wb  = (unsigned short*)(ws + 16777216);      // 512 KB
    unsigned short* ObA = (unsigned short*)(ws + 17301504);      // 8 MB

    prep_kernel<<<2176, 256, 0, stream>>>(K, V, W, Kb, Vb, Wb);
    attn_kernel<<<dim3(32, 16), 512, 0, stream>>>(Q, Kb, Vb, ObA);
    proj_kernel<<<dim3(64, 8), 256, 0, stream>>>(ObA, Wb, bo, out);
}

// Round 8
// 185.208 us; speedup vs baseline: 1.1782x; 1.0223x over previous
//
#include <hip/hip_runtime.h>
#include <hip/hip_bf16.h>

#define Bn 2
#define Sn 4096
#define Dn 512
#define Hn 8

typedef _Float16 f16x8 __attribute__((ext_vector_type(8)));
typedef __fp16 fp16x2 __attribute__((ext_vector_type(2)));
typedef float f32x16 __attribute__((ext_vector_type(16)));
typedef unsigned uint2v __attribute__((ext_vector_type(2)));

// pack two f32 -> two f16 in one dword (v_cvt_pkrtz_f16_f32, 1 VALU op)
static __device__ __forceinline__ unsigned pkh(float a, float b) {
    union { fp16x2 h; unsigned u; } r;
    r.h = __builtin_amdgcn_cvt_pkrtz(a, b);
    return r.u;
}

// C-layout group pair -> A/B-fragment (K=16 shapes) via lane^32 exchange.
// f.u[0]: lanes<32 own g0, lanes>=32 partner's g1; f.u[2]: lanes<32 partner's g0, lanes>=32 own g1.
// v_permlane32_swap_b32(a,b): a_new=[a_lo, b_lo(moved up)], b_new=[a_hi(moved down), b_hi].
static __device__ __forceinline__ f16x8 xchg2(unsigned g0x, unsigned g0y,
                                              unsigned g1x, unsigned g1y, int hi) {
    union { unsigned u[4]; f16x8 v; } f;
#if __has_builtin(__builtin_amdgcn_permlane32_swap)
    uint2v rx = __builtin_amdgcn_permlane32_swap(g0x, g1x, false, false);
    uint2v ry = __builtin_amdgcn_permlane32_swap(g0y, g1y, false, false);
    f.u[0] = rx.x; f.u[1] = ry.x; f.u[2] = rx.y; f.u[3] = ry.y;
#else
    int sx = hi ? (int)g0x : (int)g1x;
    int sy = hi ? (int)g0y : (int)g1y;
    int rx = __shfl_xor(sx, 32);
    int ry = __shfl_xor(sy, 32);
    unsigned ox = hi ? g1x : g0x;
    unsigned oy = hi ? g1y : g0y;
    f.u[0] = hi ? (unsigned)rx : ox;
    f.u[1] = hi ? (unsigned)ry : oy;
    f.u[2] = hi ? ox : (unsigned)rx;
    f.u[3] = hi ? oy : (unsigned)ry;
#endif
    return f.v;
}

// ---------- unified prepass: K,V,W fp32 -> fragment-ordered f16 ----------
// blocks 0..1023: K -> Kb [bh][kt64][f=ktile*4+ks][lane][8]   (QK A-frags, K=16)
// blocks 1024..2047: V -> Vb [bh][kt64][f=dt*4+ks][lane][8]   (PV A-frags, K=16, V^T)
// blocks 2048..2175: W -> Wb [ntile16][kstep32][lane][8]      (proj B-frags, W^T)
__global__ __launch_bounds__(256) void prep_kernel(
    const float* __restrict__ K, const float* __restrict__ V, const float* __restrict__ W,
    unsigned short* __restrict__ Kb, unsigned short* __restrict__ Vb,
    unsigned short* __restrict__ Wb) {
    const int vb = blockIdx.x;
    const int tid = threadIdx.x;
    if (vb < 1024) {
        const int kt = vb & 63, bh = vb >> 6;
        const int b = bh >> 3, h = bh & 7;
        unsigned short* dst = Kb + ((size_t)bh * 64 + kt) * 4096;
#pragma unroll
        for (int i = 0; i < 2; ++i) {
            int c = tid + i * 256;
            int f = c >> 6, ln = c & 63;
            int ktile = f >> 2, ks = f & 3;
            int row = ktile * 32 + (ln & 31);
            int dk = ks * 16 + (ln >> 5) * 8;
            const float* src = K + ((size_t)(b * Sn + kt * 64 + row)) * Dn + h * 64 + dk;
            float4 a0 = *(const float4*)src;
            float4 a1 = *(const float4*)(src + 4);
            uint4 o;
            o.x = pkh(a0.x, a0.y); o.y = pkh(a0.z, a0.w);
            o.z = pkh(a1.x, a1.y); o.w = pkh(a1.z, a1.w);
            *(uint4*)(dst + c * 8) = o;
        }
    } else if (vb < 2048) {
        const int u = vb - 1024;
        const int kt = u & 63, bh = u >> 6;
        const int b = bh >> 3, h = bh & 7;
        unsigned short* dst = Vb + ((size_t)bh * 64 + kt) * 4096;
#pragma unroll
        for (int i = 0; i < 2; ++i) {
            int c = tid + i * 256;              // 0..511
            int f = c >> 6, ln = c & 63;        // frag, lane
            int dt = f >> 2, ks = f & 3;
            int dk = dt * 32 + (ln & 31);
            int key0 = ks * 16 + (ln >> 5) * 8;
            const float* src = V + ((size_t)(b * Sn + kt * 64 + key0)) * Dn + h * 64 + dk;
            uint4 o;
            o.x = pkh(src[0 * Dn], src[1 * Dn]);
            o.y = pkh(src[2 * Dn], src[3 * Dn]);
            o.z = pkh(src[4 * Dn], src[5 * Dn]);
            o.w = pkh(src[6 * Dn], src[7 * Dn]);
            *(uint4*)(dst + c * 8) = o;
        }
    } else {
        int c = (vb - 2048) * 256 + tid;   // 0..32767
        int ln = c & 63, f = c >> 6;
        int ntile = f >> 5, ks = f & 31;
        int n = ntile * 32 + (ln & 31);
        int k0 = ks * 16 + (ln >> 5) * 8;
        uint4 o;
        o.x = pkh(W[(size_t)(k0 + 0) * Dn + n], W[(size_t)(k0 + 1) * Dn + n]);
        o.y = pkh(W[(size_t)(k0 + 2) * Dn + n], W[(size_t)(k0 + 3) * Dn + n]);
        o.z = pkh(W[(size_t)(k0 + 4) * Dn + n], W[(size_t)(k0 + 5) * Dn + n]);
        o.w = pkh(W[(size_t)(k0 + 6) * Dn + n], W[(size_t)(k0 + 7) * Dn + n]);
        *(uint4*)(Wb + c * 8) = o;
    }
}

// ---------- flash attention: f16 K=16, permlane P-transpose, single-barrier dbuf ----------
// block 512 thr = 8 waves: waves 0-3 keys 0..2047, waves 4-7 keys 2048..4095;
// wave pair (w4, w4+4) shares q-tile; pair-reduce via LDS at end.
__global__ __launch_bounds__(512, 4) void attn_kernel(
    const float* __restrict__ Q,
    const unsigned short* __restrict__ Kb,
    const unsigned short* __restrict__ Vb,
    unsigned short* __restrict__ ObA) {   // [gmtile 256][ksg 32][lane 64][8]
    // double buffer: buf b at b*16384; within buf: K half at half*4096, V half at 8192+half*4096
    __shared__ __align__(16) unsigned short KV[32768];  // 64 KB

    const int qt = blockIdx.x;
    const int bh = blockIdx.y;
    const int b = bh >> 3, h = bh & 7;
    const int tid = threadIdx.x;
    const int wg = tid >> 6;
    const int half = wg >> 2;
    const int w4 = wg & 3;
    const int lane = tid & 63;
    const int q = lane & 31;
    const int hi = lane >> 5;
    const int q0 = qt * 128 + w4 * 32;
    const int th = tid & 255;
    const float cexp = 0.18033688f;  // (1/sqrt(64)) * log2(e), folded into Q

    // Q B-frags (K=16): col=q, k(dk) = ks*16 + hi*8 + j
    f16x8 qf[4];
    {
        const float* qp = Q + ((size_t)(b * Sn + q0 + q)) * Dn + h * 64 + hi * 8;
#pragma unroll
        for (int ks = 0; ks < 4; ++ks) {
            float4 a0 = *(const float4*)(qp + ks * 16);
            float4 a1 = *(const float4*)(qp + ks * 16 + 4);
            union { unsigned u[4]; f16x8 v; } f;
            f.u[0] = pkh(a0.x * cexp, a0.y * cexp);
            f.u[1] = pkh(a0.z * cexp, a0.w * cexp);
            f.u[2] = pkh(a1.x * cexp, a1.y * cexp);
            f.u[3] = pkh(a1.z * cexp, a1.w * cexp);
            qf[ks] = f.v;
        }
    }

    f32x16 zf;
#pragma unroll
    for (int r = 0; r < 16; ++r) zf[r] = 0.f;
    f32x16 oacc[2];
    oacc[0] = zf; oacc[1] = zf;
    float l_ = 0.f;

    const size_t tbase = ((size_t)bh * 64 + half * 32) * 4096;
    const unsigned short* kg = Kb + tbase;
    const unsigned short* vg = Vb + tbase;

    // stage tile 0 into buf0 (no barrier needed until first read)
    {
        uint4 a = *(const uint4*)(kg + th * 16);
        uint4 c = *(const uint4*)(kg + th * 16 + 8);
        uint4 d = *(const uint4*)(vg + th * 16);
        uint4 e2 = *(const uint4*)(vg + th * 16 + 8);
        unsigned short* Kb0 = KV + half * 4096;
        unsigned short* Vb0 = KV + 8192 + half * 4096;
        *(uint4*)&Kb0[th * 16] = a;
        *(uint4*)&Kb0[th * 16 + 8] = c;
        *(uint4*)&Vb0[th * 16] = d;
        *(uint4*)&Vb0[th * 16 + 8] = e2;
    }
    // preload tile 1 into regs
    uint4 gk0 = *(const uint4*)(kg + 4096 + th * 16);
    uint4 gk1 = *(const uint4*)(kg + 4096 + th * 16 + 8);
    uint4 gv0 = *(const uint4*)(vg + 4096 + th * 16);
    uint4 gv1 = *(const uint4*)(vg + 4096 + th * 16 + 8);

    for (int it = 0; it < 32; ++it) {
        __syncthreads();   // buf[it&1] complete for all waves
        const unsigned short* Kbuf = KV + (it & 1) * 16384 + half * 4096;
        const unsigned short* Vbuf = KV + (it & 1) * 16384 + 8192 + half * 4096;

#pragma unroll
        for (int t = 0; t < 2; ++t) {
            // S^T tile t = K(tile t) . Q^T  (K=16 f16 MFMA, hoisted-zero C)
            f16x8 ka = *(const f16x8*)&Kbuf[(t * 4 + 0) * 512 + lane * 8];
            f32x16 sa = __builtin_amdgcn_mfma_f32_32x32x16_f16(ka, qf[0], zf, 0, 0, 0);
#pragma unroll
            for (int ks = 1; ks < 4; ++ks) {
                ka = *(const f16x8*)&Kbuf[(t * 4 + ks) * 512 + lane * 8];
                sa = __builtin_amdgcn_mfma_f32_32x32x16_f16(ka, qf[ks], sa, 0, 0, 0);
            }
            // p = exp2(s); lane-local l
            float e[16];
            float s0 = 0.f, s1 = 0.f;
#pragma unroll
            for (int r = 0; r < 16; r += 2) {
                e[r] = __builtin_amdgcn_exp2f(sa[r]);
                e[r + 1] = __builtin_amdgcn_exp2f(sa[r + 1]);
                s0 += e[r]; s1 += e[r + 1];
            }
            l_ += s0 + s1;
            // O^T += V^T . P^T  (K=16: B-frag from C-groups via permlane32_swap)
#pragma unroll
            for (int s2 = 0; s2 < 2; ++s2) {
                unsigned g0x = pkh(e[8 * s2 + 0], e[8 * s2 + 1]);
                unsigned g0y = pkh(e[8 * s2 + 2], e[8 * s2 + 3]);
                unsigned g1x = pkh(e[8 * s2 + 4], e[8 * s2 + 5]);
                unsigned g1y = pkh(e[8 * s2 + 6], e[8 * s2 + 7]);
                f16x8 pb = xchg2(g0x, g0y, g1x, g1y, hi);
                const int kp = t * 2 + s2;   // global ks index 0..3
                f16x8 va0 = *(const f16x8*)&Vbuf[(0 * 4 + kp) * 512 + lane * 8];
                f16x8 va1 = *(const f16x8*)&Vbuf[(1 * 4 + kp) * 512 + lane * 8];
                oacc[0] = __builtin_amdgcn_mfma_f32_32x32x16_f16(va0, pb, oacc[0], 0, 0, 0);
                oacc[1] = __builtin_amdgcn_mfma_f32_32x32x16_f16(va1, pb, oacc[1], 0, 0, 0);
            }
        }

        if (it < 31) {
            // write preloaded tile it+1 into the other buffer (its last reader
            // finished before barrier(it); its next reader waits at barrier(it+1))
            unsigned short* nK = KV + ((it + 1) & 1) * 16384 + half * 4096;
            unsigned short* nV = KV + ((it + 1) & 1) * 16384 + 8192 + half * 4096;
            *(uint4*)&nK[th * 16] = gk0;
            *(uint4*)&nK[th * 16 + 8] = gk1;
            *(uint4*)&nV[th * 16] = gv0;
            *(uint4*)&nV[th * 16 + 8] = gv1;
            if (it < 30) {
                const unsigned short* ks_ = kg + (size_t)(it + 2) * 4096;
                const unsigned short* vs_ = vg + (size_t)(it + 2) * 4096;
                gk0 = *(const uint4*)(ks_ + th * 16);
                gk1 = *(const uint4*)(ks_ + th * 16 + 8);
                gv0 = *(const uint4*)(vs_ + th * 16);
                gv1 = *(const uint4*)(vs_ + th * 16 + 8);
            }
        }
    }

    // pair reduction through LDS (reuse KV: rp = 8192 floats, Ls at float ofs 8192)
    __syncthreads();
    float* rp = (float*)KV + w4 * 2048;
    float* Ls = (float*)KV + 8192 + w4 * 64;
    if (half) {
#pragma unroll
        for (int g = 0; g < 8; ++g) {
            float4 v;
            v.x = oacc[g >> 2][(g & 3) * 4 + 0];
            v.y = oacc[g >> 2][(g & 3) * 4 + 1];
            v.z = oacc[g >> 2][(g & 3) * 4 + 2];
            v.w = oacc[g >> 2][(g & 3) * 4 + 3];
            *(float4*)&rp[g * 256 + lane * 4] = v;
        }
        Ls[lane] = l_;
    }
    __syncthreads();
    if (!half) {
#pragma unroll
        for (int g = 0; g < 8; ++g) {
            float4 v = *(const float4*)&rp[g * 256 + lane * 4];
            oacc[g >> 2][(g & 3) * 4 + 0] += v.x;
            oacc[g >> 2][(g & 3) * 4 + 1] += v.y;
            oacc[g >> 2][(g & 3) * 4 + 2] += v.z;
            oacc[g >> 2][(g & 3) * 4 + 3] += v.w;
        }
        l_ += Ls[lane];
        l_ += __shfl_xor(l_, 32);
        const float li = 1.f / l_;
        const int gm = b * 128 + qt * 4 + w4;
#pragma unroll
        for (int ksg = 0; ksg < 4; ++ksg) {
            const int dt = ksg >> 1, k2 = ksg & 1;
            unsigned g0x = pkh(oacc[dt][8 * k2 + 0] * li, oacc[dt][8 * k2 + 1] * li);
            unsigned g0y = pkh(oacc[dt][8 * k2 + 2] * li, oacc[dt][8 * k2 + 3] * li);
            unsigned g1x = pkh(oacc[dt][8 * k2 + 4] * li, oacc[dt][8 * k2 + 5] * li);
            unsigned g1y = pkh(oacc[dt][8 * k2 + 6] * li, oacc[dt][8 * k2 + 7] * li);
            f16x8 frag = xchg2(g0x, g0y, g1x, g1y, hi);
            union { f16x8 v; uint4 u; } fu; fu.v = frag;
            *(uint4*)&ObA[((size_t)(gm * 32 + h * 4 + ksg) * 64 + lane) * 8] = fu.u;
        }
    }
}

// ---------- projection GEMM: out = A @ W + b (A,W fragment-ordered f16) ----------
// grid (64 mt of 128 rows, 8 nt of 64 cols), block 256 (4 waves, 32 rows each).
__global__ __launch_bounds__(256) void proj_kernel(
    const unsigned short* __restrict__ ObA,  // [256][32][64][8]
    const unsigned short* __restrict__ Wb,   // [16][32][64][8]
    const float* __restrict__ bias,
    float* __restrict__ out) {
    __shared__ __align__(16) unsigned short Ash[8192];
    __shared__ __align__(16) unsigned short Wsh[4096];

    const int mt = blockIdx.x;
    const int nt = blockIdx.y;
    const int tid = threadIdx.x;
    const int w = tid >> 6;
    const int lane = tid & 63;
    const int q = lane & 31;
    const int hi = lane >> 5;

    f32x16 acc[2];
#pragma unroll
    for (int t = 0; t < 2; ++t)
#pragma unroll
        for (int r = 0; r < 16; ++r) acc[t][r] = 0.f;

    for (int kt = 0; kt < 8; ++kt) {
        __syncthreads();
#pragma unroll
        for (int i = 0; i < 4; ++i) {
            int ci = (tid >> 6) + i * 4;     // 0..15
            int ml = ci >> 2, ksl = ci & 3;
            *(uint4*)&Ash[ci * 512 + lane * 8] =
                *(const uint4*)(ObA + (((size_t)(mt * 4 + ml) * 32 + kt * 4 + ksl) * 64 + lane) * 8);
        }
#pragma unroll
        for (int i = 0; i < 2; ++i) {
            int ci = (tid >> 6) + i * 4;     // 0..7
            int ntl = ci >> 2, ksl = ci & 3;
            *(uint4*)&Wsh[ci * 512 + lane * 8] =
                *(const uint4*)(Wb + (((size_t)(nt * 2 + ntl) * 32 + kt * 4 + ksl) * 64 + lane) * 8);
        }
        __syncthreads();

#pragma unroll
        for (int ks = 0; ks < 4; ++ks) {
            f16x8 a  = *(const f16x8*)&Ash[(w * 4 + ks) * 512 + lane * 8];
            f16x8 b0 = *(const f16x8*)&Wsh[(0 * 4 + ks) * 512 + lane * 8];
            f16x8 b1 = *(const f16x8*)&Wsh[(4 + ks) * 512 + lane * 8];
            acc[0] = __builtin_amdgcn_mfma_f32_32x32x16_f16(a, b0, acc[0], 0, 0, 0);
            acc[1] = __builtin_amdgcn_mfma_f32_32x32x16_f16(a, b1, acc[1], 0, 0, 0);
        }
    }

#pragma unroll
    for (int ntl = 0; ntl < 2; ++ntl) {
        int col = nt * 64 + ntl * 32 + q;
        float bv = bias[col];
#pragma unroll
        for (int reg = 0; reg < 16; ++reg) {
            int row = mt * 128 + w * 32 + (reg & 3) + 8 * (reg >> 2) + 4 * hi;
            out[(size_t)row * Dn + col] = acc[ntl][reg] + bv;
        }
    }
}

extern "C" void kernel_launch(void* const* d_in, const int* in_sizes, int n_in,
                              void* d_out, int out_size, void* d_ws, size_t ws_size,
                              hipStream_t stream) {
    const float* Q = (const float*)d_in[0];
    const float* K = (const float*)d_in[1];
    const float* V = (const float*)d_in[2];
    const float* W = (const float*)d_in[3];
    const float* bo = (const float*)d_in[4];
    float* out = (float*)d_out;

    char* ws = (char*)d_ws;
    unsigned short* Kb  = (unsigned short*)(ws);                 // 8 MB
    unsigned short* Vb  = (unsigned short*)(ws + 8388608);       // 8 MB
    unsigned short* Wb  = (unsigned short*)(ws + 16777216);      // 512 KB
    unsigned short* ObA = (unsigned short*)(ws + 17301504);      // 8 MB

    prep_kernel<<<2176, 256, 0, stream>>>(K, V, W, Kb, Vb, Wb);
    attn_kernel<<<dim3(32, 16), 512, 0, stream>>>(Q, Kb, Vb, ObA);
    proj_kernel<<<dim3(64, 8), 256, 0, stream>>>(ObA, Wb, bo, out);
}

// Round 9
// 185.206 us; speedup vs baseline: 1.1783x; 1.0000x over previous
//
#include <hip/hip_runtime.h>
#include <hip/hip_bf16.h>

#define Bn 2
#define Sn 4096
#define Dn 512
#define Hn 8

typedef _Float16 f16x8 __attribute__((ext_vector_type(8)));
typedef __fp16 fp16x2 __attribute__((ext_vector_type(2)));
typedef float f32x16 __attribute__((ext_vector_type(16)));
typedef unsigned uint2v __attribute__((ext_vector_type(2)));

#if __has_builtin(__builtin_amdgcn_global_load_lds)
#define HAS_GLL 1
typedef const __attribute__((address_space(1))) unsigned int* gas1_t;
typedef __attribute__((address_space(3))) unsigned int* las3_t;
// async 16B/lane global->LDS: LDS dst = uniform base + lane*16
static __device__ __forceinline__ void ld_lds16(const void* g, void* l) {
    __builtin_amdgcn_global_load_lds((gas1_t)g, (las3_t)l, 16, 0, 0);
}
#else
#define HAS_GLL 0
#endif

// pack two f32 -> two f16 in one dword (v_cvt_pkrtz_f16_f32, 1 VALU op)
static __device__ __forceinline__ unsigned pkh(float a, float b) {
    union { fp16x2 h; unsigned u; } r;
    r.h = __builtin_amdgcn_cvt_pkrtz(a, b);
    return r.u;
}

// C-layout group pair -> A/B-fragment (K=16 shapes) via lane^32 exchange.
static __device__ __forceinline__ f16x8 xchg2(unsigned g0x, unsigned g0y,
                                              unsigned g1x, unsigned g1y, int hi) {
    union { unsigned u[4]; f16x8 v; } f;
#if __has_builtin(__builtin_amdgcn_permlane32_swap)
    uint2v rx = __builtin_amdgcn_permlane32_swap(g0x, g1x, false, false);
    uint2v ry = __builtin_amdgcn_permlane32_swap(g0y, g1y, false, false);
    f.u[0] = rx.x; f.u[1] = ry.x; f.u[2] = rx.y; f.u[3] = ry.y;
#else
    int sx = hi ? (int)g0x : (int)g1x;
    int sy = hi ? (int)g0y : (int)g1y;
    int rx = __shfl_xor(sx, 32);
    int ry = __shfl_xor(sy, 32);
    unsigned ox = hi ? g1x : g0x;
    unsigned oy = hi ? g1y : g0y;
    f.u[0] = hi ? (unsigned)rx : ox;
    f.u[1] = hi ? (unsigned)ry : oy;
    f.u[2] = hi ? ox : (unsigned)rx;
    f.u[3] = hi ? oy : (unsigned)ry;
#endif
    return f.v;
}

// ---------- unified prepass: K,V,W fp32 -> fragment-ordered f16 ----------
__global__ __launch_bounds__(256) void prep_kernel(
    const float* __restrict__ K, const float* __restrict__ V, const float* __restrict__ W,
    unsigned short* __restrict__ Kb, unsigned short* __restrict__ Vb,
    unsigned short* __restrict__ Wb) {
    const int vb = blockIdx.x;
    const int tid = threadIdx.x;
    if (vb < 1024) {
        const int kt = vb & 63, bh = vb >> 6;
        const int b = bh >> 3, h = bh & 7;
        unsigned short* dst = Kb + ((size_t)bh * 64 + kt) * 4096;
#pragma unroll
        for (int i = 0; i < 2; ++i) {
            int c = tid + i * 256;
            int f = c >> 6, ln = c & 63;
            int ktile = f >> 2, ks = f & 3;
            int row = ktile * 32 + (ln & 31);
            int dk = ks * 16 + (ln >> 5) * 8;
            const float* src = K + ((size_t)(b * Sn + kt * 64 + row)) * Dn + h * 64 + dk;
            float4 a0 = *(const float4*)src;
            float4 a1 = *(const float4*)(src + 4);
            uint4 o;
            o.x = pkh(a0.x, a0.y); o.y = pkh(a0.z, a0.w);
            o.z = pkh(a1.x, a1.y); o.w = pkh(a1.z, a1.w);
            *(uint4*)(dst + c * 8) = o;
        }
    } else if (vb < 2048) {
        const int u = vb - 1024;
        const int kt = u & 63, bh = u >> 6;
        const int b = bh >> 3, h = bh & 7;
        unsigned short* dst = Vb + ((size_t)bh * 64 + kt) * 4096;
#pragma unroll
        for (int i = 0; i < 2; ++i) {
            int c = tid + i * 256;
            int f = c >> 6, ln = c & 63;
            int dt = f >> 2, ks = f & 3;
            int dk = dt * 32 + (ln & 31);
            int key0 = ks * 16 + (ln >> 5) * 8;
            const float* src = V + ((size_t)(b * Sn + kt * 64 + key0)) * Dn + h * 64 + dk;
            uint4 o;
            o.x = pkh(src[0 * Dn], src[1 * Dn]);
            o.y = pkh(src[2 * Dn], src[3 * Dn]);
            o.z = pkh(src[4 * Dn], src[5 * Dn]);
            o.w = pkh(src[6 * Dn], src[7 * Dn]);
            *(uint4*)(dst + c * 8) = o;
        }
    } else {
        int c = (vb - 2048) * 256 + tid;
        int ln = c & 63, f = c >> 6;
        int ntile = f >> 5, ks = f & 31;
        int n = ntile * 32 + (ln & 31);
        int k0 = ks * 16 + (ln >> 5) * 8;
        uint4 o;
        o.x = pkh(W[(size_t)(k0 + 0) * Dn + n], W[(size_t)(k0 + 1) * Dn + n]);
        o.y = pkh(W[(size_t)(k0 + 2) * Dn + n], W[(size_t)(k0 + 3) * Dn + n]);
        o.z = pkh(W[(size_t)(k0 + 4) * Dn + n], W[(size_t)(k0 + 5) * Dn + n]);
        o.w = pkh(W[(size_t)(k0 + 6) * Dn + n], W[(size_t)(k0 + 7) * Dn + n]);
        *(uint4*)(Wb + c * 8) = o;
    }
}

// ---------- flash attention: f16 K=16, async LDS staging, interleaved S chains ----------
// block 512 thr = 8 waves: waves 0-3 keys 0..2047, waves 4-7 keys 2048..4095;
// wave pair (w4, w4+4) shares q-tile; pair-reduce via LDS at end.
__global__ __launch_bounds__(512, 4) void attn_kernel(
    const float* __restrict__ Q,
    const unsigned short* __restrict__ Kb,
    const unsigned short* __restrict__ Vb,
    unsigned short* __restrict__ ObA) {   // [gmtile 256][ksg 32][lane 64][8]
    // double buffer: buf b at b*16384 ushorts; K half at half*4096, V at +8192
    __shared__ __align__(16) unsigned short KV[32768];  // 64 KB

    const int qt = blockIdx.x;
    const int bh = blockIdx.y;
    const int b = bh >> 3, h = bh & 7;
    const int tid = threadIdx.x;
    const int wg = tid >> 6;
    const int half = wg >> 2;
    const int w4 = wg & 3;
    const int lane = tid & 63;
    const int q = lane & 31;
    const int hi = lane >> 5;
    const int q0 = qt * 128 + w4 * 32;
    const float cexp = 0.18033688f;  // (1/sqrt(64)) * log2(e), folded into Q

    // Q B-frags (K=16): col=q, k(dk) = ks*16 + hi*8 + j
    f16x8 qf[4];
    {
        const float* qp = Q + ((size_t)(b * Sn + q0 + q)) * Dn + h * 64 + hi * 8;
#pragma unroll
        for (int ks = 0; ks < 4; ++ks) {
            float4 a0 = *(const float4*)(qp + ks * 16);
            float4 a1 = *(const float4*)(qp + ks * 16 + 4);
            union { unsigned u[4]; f16x8 v; } f;
            f.u[0] = pkh(a0.x * cexp, a0.y * cexp);
            f.u[1] = pkh(a0.z * cexp, a0.w * cexp);
            f.u[2] = pkh(a1.x * cexp, a1.y * cexp);
            f.u[3] = pkh(a1.z * cexp, a1.w * cexp);
            qf[ks] = f.v;
        }
    }

    f32x16 zf;
#pragma unroll
    for (int r = 0; r < 16; ++r) zf[r] = 0.f;
    f32x16 oacc[2];
    oacc[0] = zf; oacc[1] = zf;
    float l_ = 0.f;

    const size_t tbase = ((size_t)bh * 64 + half * 32) * 4096;
    // wave-local staging region: wave w4 covers ushorts [w4*1024, w4*1024+1024) of each tile
    const unsigned short* kgw = Kb + tbase + w4 * 1024;
    const unsigned short* vgw = Vb + tbase + w4 * 1024;
    const int lK = half * 4096 + w4 * 1024;       // ushort offset within a buffer
    const int lV = 8192 + half * 4096 + w4 * 1024;

#if HAS_GLL
#define STAGE(itx, bb) { \
    const unsigned short* ksp = kgw + (size_t)(itx) * 4096 + lane * 8; \
    const unsigned short* vsp = vgw + (size_t)(itx) * 4096 + lane * 8; \
    unsigned short* lk = &KV[(bb) * 16384 + lK]; \
    unsigned short* lv = &KV[(bb) * 16384 + lV]; \
    ld_lds16(ksp, lk); ld_lds16(ksp + 512, lk + 512); \
    ld_lds16(vsp, lv); ld_lds16(vsp + 512, lv + 512); }
    STAGE(0, 0);
#else
    const int th = tid & 255;
#define STAGE(itx, bb) { \
    const unsigned short* ksp = kgw - (size_t)w4 * 1024 + (size_t)(itx) * 4096; \
    const unsigned short* vsp = vgw - (size_t)w4 * 1024 + (size_t)(itx) * 4096; \
    uint4 a0 = *(const uint4*)(ksp + th * 8); \
    uint4 a1 = *(const uint4*)(ksp + 2048 + th * 8); \
    uint4 a2 = *(const uint4*)(vsp + th * 8); \
    uint4 a3 = *(const uint4*)(vsp + 2048 + th * 8); \
    unsigned short* lk = &KV[(bb) * 16384 + half * 4096]; \
    unsigned short* lv = &KV[(bb) * 16384 + 8192 + half * 4096]; \
    *(uint4*)&lk[th * 8] = a0; *(uint4*)&lk[2048 + th * 8] = a1; \
    *(uint4*)&lv[th * 8] = a2; *(uint4*)&lv[2048 + th * 8] = a3; }
    STAGE(0, 0);
#endif

    for (int it = 0; it < 32; ++it) {
        __syncthreads();   // drains staging (vmcnt/lgkm); buf[it&1] complete; prev readers done
        const unsigned short* Kbuf = KV + (it & 1) * 16384 + half * 4096;
        const unsigned short* Vbuf = Kbuf + 8192;
        if (it < 31) STAGE(it + 1, (it + 1) & 1);

        // S^T: both 32-key tiles' chains interleaved (2 independent MFMA chains)
        f32x16 sa0, sa1;
        {
            f16x8 ka = *(const f16x8*)&Kbuf[0 * 512 + lane * 8];
            f16x8 kb = *(const f16x8*)&Kbuf[4 * 512 + lane * 8];
            sa0 = __builtin_amdgcn_mfma_f32_32x32x16_f16(ka, qf[0], zf, 0, 0, 0);
            sa1 = __builtin_amdgcn_mfma_f32_32x32x16_f16(kb, qf[0], zf, 0, 0, 0);
#pragma unroll
            for (int ks = 1; ks < 4; ++ks) {
                ka = *(const f16x8*)&Kbuf[(0 + ks) * 512 + lane * 8];
                kb = *(const f16x8*)&Kbuf[(4 + ks) * 512 + lane * 8];
                sa0 = __builtin_amdgcn_mfma_f32_32x32x16_f16(ka, qf[ks], sa0, 0, 0, 0);
                sa1 = __builtin_amdgcn_mfma_f32_32x32x16_f16(kb, qf[ks], sa1, 0, 0, 0);
            }
        }
        // p = exp2(s); lane-local l
        float e0[16], e1[16];
        float s0 = 0.f, s1 = 0.f;
#pragma unroll
        for (int r = 0; r < 16; ++r) { e0[r] = __builtin_amdgcn_exp2f(sa0[r]); s0 += e0[r]; }
#pragma unroll
        for (int r = 0; r < 16; ++r) { e1[r] = __builtin_amdgcn_exp2f(sa1[r]); s1 += e1[r]; }
        l_ += s0 + s1;

        // O^T += V^T . P^T  (K=16: B-frags from C-groups via permlane32_swap)
#pragma unroll
        for (int kp = 0; kp < 4; ++kp) {
            const float* e = (kp < 2) ? e0 : e1;
            const int s2 = kp & 1;
            unsigned g0x = pkh(e[8 * s2 + 0], e[8 * s2 + 1]);
            unsigned g0y = pkh(e[8 * s2 + 2], e[8 * s2 + 3]);
            unsigned g1x = pkh(e[8 * s2 + 4], e[8 * s2 + 5]);
            unsigned g1y = pkh(e[8 * s2 + 6], e[8 * s2 + 7]);
            f16x8 pb = xchg2(g0x, g0y, g1x, g1y, hi);
            f16x8 va0 = *(const f16x8*)&Vbuf[(0 + kp) * 512 + lane * 8];
            f16x8 va1 = *(const f16x8*)&Vbuf[(4 + kp) * 512 + lane * 8];
            oacc[0] = __builtin_amdgcn_mfma_f32_32x32x16_f16(va0, pb, oacc[0], 0, 0, 0);
            oacc[1] = __builtin_amdgcn_mfma_f32_32x32x16_f16(va1, pb, oacc[1], 0, 0, 0);
        }
    }

    // pair reduction through LDS (reuse KV: rp = 8192 floats, Ls at float ofs 8192)
    __syncthreads();
    float* rp = (float*)KV + w4 * 2048;
    float* Ls = (float*)KV + 8192 + w4 * 64;
    if (half) {
#pragma unroll
        for (int g = 0; g < 8; ++g) {
            float4 v;
            v.x = oacc[g >> 2][(g & 3) * 4 + 0];
            v.y = oacc[g >> 2][(g & 3) * 4 + 1];
            v.z = oacc[g >> 2][(g & 3) * 4 + 2];
            v.w = oacc[g >> 2][(g & 3) * 4 + 3];
            *(float4*)&rp[g * 256 + lane * 4] = v;
        }
        Ls[lane] = l_;
    }
    __syncthreads();
    if (!half) {
#pragma unroll
        for (int g = 0; g < 8; ++g) {
            float4 v = *(const float4*)&rp[g * 256 + lane * 4];
            oacc[g >> 2][(g & 3) * 4 + 0] += v.x;
            oacc[g >> 2][(g & 3) * 4 + 1] += v.y;
            oacc[g >> 2][(g & 3) * 4 + 2] += v.z;
            oacc[g >> 2][(g & 3) * 4 + 3] += v.w;
        }
        l_ += Ls[lane];
        l_ += __shfl_xor(l_, 32);
        const float li = 1.f / l_;
        const int gm = b * 128 + qt * 4 + w4;
#pragma unroll
        for (int ksg = 0; ksg < 4; ++ksg) {
            const int dt = ksg >> 1, k2 = ksg & 1;
            unsigned g0x = pkh(oacc[dt][8 * k2 + 0] * li, oacc[dt][8 * k2 + 1] * li);
            unsigned g0y = pkh(oacc[dt][8 * k2 + 2] * li, oacc[dt][8 * k2 + 3] * li);
            unsigned g1x = pkh(oacc[dt][8 * k2 + 4] * li, oacc[dt][8 * k2 + 5] * li);
            unsigned g1y = pkh(oacc[dt][8 * k2 + 6] * li, oacc[dt][8 * k2 + 7] * li);
            f16x8 frag = xchg2(g0x, g0y, g1x, g1y, hi);
            union { f16x8 v; uint4 u; } fu; fu.v = frag;
            *(uint4*)&ObA[((size_t)(gm * 32 + h * 4 + ksg) * 64 + lane) * 8] = fu.u;
        }
    }
}

// ---------- projection GEMM: out = A @ W + b (A,W fragment-ordered f16) ----------
__global__ __launch_bounds__(256) void proj_kernel(
    const unsigned short* __restrict__ ObA,  // [256][32][64][8]
    const unsigned short* __restrict__ Wb,   // [16][32][64][8]
    const float* __restrict__ bias,
    float* __restrict__ out) {
    __shared__ __align__(16) unsigned short Ash[8192];
    __shared__ __align__(16) unsigned short Wsh[4096];

    const int mt = blockIdx.x;
    const int nt = blockIdx.y;
    const int tid = threadIdx.x;
    const int w = tid >> 6;
    const int lane = tid & 63;
    const int q = lane & 31;
    const int hi = lane >> 5;

    f32x16 acc[2];
#pragma unroll
    for (int t = 0; t < 2; ++t)
#pragma unroll
        for (int r = 0; r < 16; ++r) acc[t][r] = 0.f;

    for (int kt = 0; kt < 8; ++kt) {
        __syncthreads();
#pragma unroll
        for (int i = 0; i < 4; ++i) {
            int ci = (tid >> 6) + i * 4;
            int ml = ci >> 2, ksl = ci & 3;
            *(uint4*)&Ash[ci * 512 + lane * 8] =
                *(const uint4*)(ObA + (((size_t)(mt * 4 + ml) * 32 + kt * 4 + ksl) * 64 + lane) * 8);
        }
#pragma unroll
        for (int i = 0; i < 2; ++i) {
            int ci = (tid >> 6) + i * 4;
            int ntl = ci >> 2, ksl = ci & 3;
            *(uint4*)&Wsh[ci * 512 + lane * 8] =
                *(const uint4*)(Wb + (((size_t)(nt * 2 + ntl) * 32 + kt * 4 + ksl) * 64 + lane) * 8);
        }
        __syncthreads();

#pragma unroll
        for (int ks = 0; ks < 4; ++ks) {
            f16x8 a  = *(const f16x8*)&Ash[(w * 4 + ks) * 512 + lane * 8];
            f16x8 b0 = *(const f16x8*)&Wsh[(0 * 4 + ks) * 512 + lane * 8];
            f16x8 b1 = *(const f16x8*)&Wsh[(4 + ks) * 512 + lane * 8];
            acc[0] = __builtin_amdgcn_mfma_f32_32x32x16_f16(a, b0, acc[0], 0, 0, 0);
            acc[1] = __builtin_amdgcn_mfma_f32_32x32x16_f16(a, b1, acc[1], 0, 0, 0);
        }
    }

#pragma unroll
    for (int ntl = 0; ntl < 2; ++ntl) {
        int col = nt * 64 + ntl * 32 + q;
        float bv = bias[col];
#pragma unroll
        for (int reg = 0; reg < 16; ++reg) {
            int row = mt * 128 + w * 32 + (reg & 3) + 8 * (reg >> 2) + 4 * hi;
            out[(size_t)row * Dn + col] = acc[ntl][reg] + bv;
        }
    }
}

extern "C" void kernel_launch(void* const* d_in, const int* in_sizes, int n_in,
                              void* d_out, int out_size, void* d_ws, size_t ws_size,
                              hipStream_t stream) {
    const float* Q = (const float*)d_in[0];
    const float* K = (const float*)d_in[1];
    const float* V = (const float*)d_in[2];
    const float* W = (const float*)d_in[3];
    const float* bo = (const float*)d_in[4];
    float* out = (float*)d_out;

    char* ws = (char*)d_ws;
    unsigned short* Kb  = (unsigned short*)(ws);                 // 8 MB
    unsigned short* Vb  = (unsigned short*)(ws + 8388608);       // 8 MB
    unsigned short* Wb  = (unsigned short*)(ws + 16777216);      // 512 KB
    unsigned short* ObA = (unsigned short*)(ws + 17301504);      // 8 MB

    prep_kernel<<<2176, 256, 0, stream>>>(K, V, W, Kb, Vb, Wb);
    attn_kernel<<<dim3(32, 16), 512, 0, stream>>>(Q, Kb, Vb, ObA);
    proj_kernel<<<dim3(64, 8), 256, 0, stream>>>(ObA, Wb, bo, out);
}